// Round 6
// baseline (7293.267 us; speedup 1.0000x reference)
//
#include <hip/hip_runtime.h>
#include <math.h>

#define NQ2 2048      // nx = nq = 2048
#define NT  4096      // nx + nq
#define NUU 16
#define FEPS 0.01f
#define NB  64
#define NBLK 32       // 2048 / 64 (solve blocking)
#define NSB 128       // cholesky super-block
#define NSBLK 16      // 2048 / 128
#define GCH 16        // split-K chunks for transposed GEMVs

typedef __attribute__((ext_vector_type(8))) short short8;
typedef __attribute__((ext_vector_type(4))) float floatx4;

__device__ __forceinline__ float readlane_f(float v, int lane) {
  return __int_as_float(__builtin_amdgcn_readlane(__float_as_int(v), lane));
}

__device__ __forceinline__ unsigned short f2bf(float x) {
  unsigned u = __float_as_uint(x);
  unsigned r = u + 0x7FFFu + ((u >> 16) & 1u);
  return (unsigned short)(r >> 16);
}
__device__ __forceinline__ float bf2f(unsigned short h) {
  return __uint_as_float(((unsigned)h) << 16);
}

// ---------------- reductions ----------------
__device__ __forceinline__ float wave_reduce(float v) {
#pragma unroll
  for (int off = 32; off > 0; off >>= 1) v += __shfl_down(v, off, 64);
  return v;
}

__device__ __forceinline__ float block_reduce_256(float v) {
  __shared__ float sm[4];
  v = wave_reduce(v);
  if ((threadIdx.x & 63) == 0) sm[threadIdx.x >> 6] = v;
  __syncthreads();
  return (threadIdx.x == 0) ? (sm[0] + sm[1] + sm[2] + sm[3]) : 0.0f;
}

// ---------------- lam: inv(0.5*(||X2 row||^2 + eps)) ----------------
__global__ __launch_bounds__(256) void lam_kernel(const float* __restrict__ X,
                                                  float* __restrict__ invlam) {
  int row = blockIdx.x;
  const float* xr = X + (size_t)(NQ2 + row) * NT;
  float s = 0.f;
  for (int k = threadIdx.x * 4; k < NT; k += 1024) {
    float4 v = *(const float4*)(xr + k);
    s += v.x * v.x + v.y * v.y + v.z * v.z + v.w * v.w;
  }
  float tot = block_reduce_256(s);
  if (threadIdx.x == 0) invlam[row] = 1.0f / (0.5f * (tot + FEPS));
}

// ---------------- split-K transposed GEMV ----------------
__global__ __launch_bounds__(256) void tgemv_part_kernel(const float* __restrict__ A,
                                                         const float* __restrict__ v,
                                                         float* __restrict__ part) {
  int col = blockIdx.x * 256 + threadIdx.x;
  int ch = blockIdx.y;
  int i0 = ch * (NQ2 / GCH), i1 = i0 + NQ2 / GCH;
  float s = 0.f;
#pragma unroll 4
  for (int i = i0; i < i1; i++) s = fmaf(A[(size_t)i * NQ2 + col], v[i], s);
  part[(size_t)ch * NQ2 + col] = s;
}

// FM 0: c = sum*invlam + D12 u   FM 1: r += 0.5*sum   FM 2: dst = sum
template <int FM>
__global__ __launch_bounds__(256) void finish_kernel(const float* __restrict__ part,
                                                     const float* __restrict__ invlam,
                                                     const float* __restrict__ D12,
                                                     const float* __restrict__ u,
                                                     float* __restrict__ dst) {
  int col = blockIdx.x * 256 + threadIdx.x;
  float s = 0.f;
#pragma unroll
  for (int ch = 0; ch < GCH; ch++) s += part[(size_t)ch * NQ2 + col];
  if (FM == 0) {
    float d = 0.f;
#pragma unroll
    for (int j = 0; j < NUU; j++) d += D12[(size_t)col * NUU + j] * u[j];
    dst[col] = s * invlam[col] + d;
  } else if (FM == 1) {
    dst[col] += 0.5f * s;
  } else {
    dst[col] = s;
  }
}

// ============ MFMA SYRK (bf16 hi/lo split): C = A A^T (+eps diag), lower 128-tiles ====
__global__ __launch_bounds__(256) void syrk_mfma_kernel(const float* __restrict__ A,
                                                        int lda, int K,
                                                        float* __restrict__ C, float eps) {
  int L = blockIdx.x;
  int bi = (int)((sqrtf(8.0f * (float)L + 1.0f) - 1.0f) * 0.5f);
  while ((bi + 1) * (bi + 2) / 2 <= L) bi++;
  while (bi * (bi + 1) / 2 > L) bi--;
  int bj = L - bi * (bi + 1) / 2;
  int row0 = bi * 128, col0 = bj * 128;

  __shared__ __align__(16) short Ah[4096], Al[4096], Bh[4096], Bl[4096];

  int tid = threadIdx.x;
  int l = tid & 63;
  int w = tid >> 6;
  int wr = w >> 1, wc = w & 1;

  int g0 = tid, g1 = tid + 256;
  int ar0 = (g0 >> 6) * 16 + (g0 & 15), ak0 = ((g0 >> 4) & 3) * 8;
  int ar1 = (g1 >> 6) * 16 + (g1 & 15), ak1 = ((g1 >> 4) & 3) * 8;

  const float* pa0 = A + (size_t)(row0 + ar0) * lda + ak0;
  const float* pa1 = A + (size_t)(row0 + ar1) * lda + ak1;
  const float* pb0 = A + (size_t)(col0 + ar0) * lda + ak0;
  const float* pb1 = A + (size_t)(col0 + ar1) * lda + ak1;

  floatx4 acc[4][4];
#pragma unroll
  for (int m = 0; m < 4; m++)
#pragma unroll
    for (int n = 0; n < 4; n++) acc[m][n] = (floatx4){0.f, 0.f, 0.f, 0.f};

  float xa0[8], xa1[8], xb0[8], xb1[8];
  {
    float4 t0 = *(const float4*)(pa0), t1 = *(const float4*)(pa0 + 4);
    xa0[0]=t0.x; xa0[1]=t0.y; xa0[2]=t0.z; xa0[3]=t0.w; xa0[4]=t1.x; xa0[5]=t1.y; xa0[6]=t1.z; xa0[7]=t1.w;
    t0 = *(const float4*)(pa1); t1 = *(const float4*)(pa1 + 4);
    xa1[0]=t0.x; xa1[1]=t0.y; xa1[2]=t0.z; xa1[3]=t0.w; xa1[4]=t1.x; xa1[5]=t1.y; xa1[6]=t1.z; xa1[7]=t1.w;
    t0 = *(const float4*)(pb0); t1 = *(const float4*)(pb0 + 4);
    xb0[0]=t0.x; xb0[1]=t0.y; xb0[2]=t0.z; xb0[3]=t0.w; xb0[4]=t1.x; xb0[5]=t1.y; xb0[6]=t1.z; xb0[7]=t1.w;
    t0 = *(const float4*)(pb1); t1 = *(const float4*)(pb1 + 4);
    xb1[0]=t0.x; xb1[1]=t0.y; xb1[2]=t0.z; xb1[3]=t0.w; xb1[4]=t1.x; xb1[5]=t1.y; xb1[6]=t1.z; xb1[7]=t1.w;
  }

  for (int k0 = 0; k0 < K; k0 += 32) {
    __syncthreads();
    {
      short8 h, lo;
#pragma unroll
      for (int j = 0; j < 8; j++) { unsigned short hb = f2bf(xa0[j]); h[j] = (short)hb; lo[j] = (short)f2bf(xa0[j] - bf2f(hb)); }
      *(short8*)&Ah[g0 * 8] = h; *(short8*)&Al[g0 * 8] = lo;
#pragma unroll
      for (int j = 0; j < 8; j++) { unsigned short hb = f2bf(xa1[j]); h[j] = (short)hb; lo[j] = (short)f2bf(xa1[j] - bf2f(hb)); }
      *(short8*)&Ah[g1 * 8] = h; *(short8*)&Al[g1 * 8] = lo;
#pragma unroll
      for (int j = 0; j < 8; j++) { unsigned short hb = f2bf(xb0[j]); h[j] = (short)hb; lo[j] = (short)f2bf(xb0[j] - bf2f(hb)); }
      *(short8*)&Bh[g0 * 8] = h; *(short8*)&Bl[g0 * 8] = lo;
#pragma unroll
      for (int j = 0; j < 8; j++) { unsigned short hb = f2bf(xb1[j]); h[j] = (short)hb; lo[j] = (short)f2bf(xb1[j] - bf2f(hb)); }
      *(short8*)&Bh[g1 * 8] = h; *(short8*)&Bl[g1 * 8] = lo;
    }
    __syncthreads();
    if (k0 + 32 < K) {
      const float* q = pa0 + k0 + 32;
      float4 t0 = *(const float4*)(q), t1 = *(const float4*)(q + 4);
      xa0[0]=t0.x; xa0[1]=t0.y; xa0[2]=t0.z; xa0[3]=t0.w; xa0[4]=t1.x; xa0[5]=t1.y; xa0[6]=t1.z; xa0[7]=t1.w;
      q = pa1 + k0 + 32; t0 = *(const float4*)(q); t1 = *(const float4*)(q + 4);
      xa1[0]=t0.x; xa1[1]=t0.y; xa1[2]=t0.z; xa1[3]=t0.w; xa1[4]=t1.x; xa1[5]=t1.y; xa1[6]=t1.z; xa1[7]=t1.w;
      q = pb0 + k0 + 32; t0 = *(const float4*)(q); t1 = *(const float4*)(q + 4);
      xb0[0]=t0.x; xb0[1]=t0.y; xb0[2]=t0.z; xb0[3]=t0.w; xb0[4]=t1.x; xb0[5]=t1.y; xb0[6]=t1.z; xb0[7]=t1.w;
      q = pb1 + k0 + 32; t0 = *(const float4*)(q); t1 = *(const float4*)(q + 4);
      xb1[0]=t0.x; xb1[1]=t0.y; xb1[2]=t0.z; xb1[3]=t0.w; xb1[4]=t1.x; xb1[5]=t1.y; xb1[6]=t1.z; xb1[7]=t1.w;
    }
    short8 amh[4], aml[4], bnh[4], bnl[4];
#pragma unroll
    for (int m = 0; m < 4; m++) {
      int ga = ((wr * 4 + m) * 64 + l) * 8;
      amh[m] = *(const short8*)&Ah[ga];
      aml[m] = *(const short8*)&Al[ga];
    }
#pragma unroll
    for (int n = 0; n < 4; n++) {
      int gb = ((wc * 4 + n) * 64 + l) * 8;
      bnh[n] = *(const short8*)&Bh[gb];
      bnl[n] = *(const short8*)&Bl[gb];
    }
#pragma unroll
    for (int m = 0; m < 4; m++)
#pragma unroll
      for (int n = 0; n < 4; n++) {
        acc[m][n] = __builtin_amdgcn_mfma_f32_16x16x32_bf16(amh[m], bnh[n], acc[m][n], 0, 0, 0);
        acc[m][n] = __builtin_amdgcn_mfma_f32_16x16x32_bf16(amh[m], bnl[n], acc[m][n], 0, 0, 0);
        acc[m][n] = __builtin_amdgcn_mfma_f32_16x16x32_bf16(aml[m], bnh[n], acc[m][n], 0, 0, 0);
      }
  }

  int lr = (l >> 4) * 4;
  int lc = l & 15;
#pragma unroll
  for (int m = 0; m < 4; m++)
#pragma unroll
    for (int n = 0; n < 4; n++)
#pragma unroll
      for (int r = 0; r < 4; r++) {
        int gi = row0 + wr * 64 + m * 16 + lr + r;
        int gj = col0 + wc * 64 + n * 16 + lc;
        float v = acc[m][n][r];
        if (gi == gj) v += eps;
        C[(size_t)gi * NQ2 + gj] = v;
      }
}

// ======== Cholesky diag: factor 128x128 in LDS + compute X = inv(L) ========
__global__ __launch_bounds__(256) void chol_diag128_kernel(float* __restrict__ M_,
                                                           float* __restrict__ Xinv, int k) {
  __shared__ float Ls[NSB][NSB + 1];
  __shared__ float Xs[NSB][NSB + 1];
  int b0 = k * NSB;
  int tid = threadIdx.x;
  for (int e = tid; e < NSB * NSB; e += 256) {
    int rr = e >> 7, cc = e & 127;
    Ls[rr][cc] = M_[(size_t)(b0 + rr) * NQ2 + b0 + cc];
    Xs[rr][cc] = 0.f;
  }
  __syncthreads();
  // factor (lower) in LDS: 2 barriers per step
#pragma unroll 1
  for (int jj = 0; jj < NSB; jj++) {
    float d = Ls[jj][jj];
    float dinv = rsqrtf(fmaxf(d, 1e-20f));
    if (tid < NSB && tid > jj) Ls[tid][jj] *= dinv;
    __syncthreads();
    int row = tid >> 1, par = tid & 1;
    if (row > jj) {
      float lr = Ls[row][jj];
#pragma unroll 1
      for (int cc = jj + 1 + par; cc <= row; cc += 2)
        Ls[row][cc] -= lr * Ls[cc][jj];
    }
    if (tid == 0) Ls[jj][jj] = d * dinv;  // sqrt(d)
    __syncthreads();
  }
  // blocked inverse: X11=inv(L11), X22=inv(L22) via lane-paired column chains
  {
    int half = tid >> 7;        // 0 -> L11, 1 -> L22
    int t2 = tid & 127;
    int col = t2 >> 1, par = t2 & 1;
    int o = half * 64;
    float diaginv = 1.0f / Ls[o + col][o + col];
    if (par == 0) Xs[o + col][o + col] = diaginv;
#pragma unroll 1
    for (int i = col + 1; i < 64; i++) {
      float s = 0.f;
#pragma unroll 1
      for (int t = col + par; t < i; t += 2) s += Ls[o + i][o + t] * Xs[o + t][o + col];
      s += __shfl_xor(s, 1);
      float xi = -s / Ls[o + i][o + i];
      if (par == 0) Xs[o + i][o + col] = xi;
    }
  }
  __syncthreads();
  // T = L21 * X11  -> temp in upper quadrant Xs[0:64][64:128]
  for (int e = tid; e < 64 * 64; e += 256) {
    int rr = e >> 6, cc = e & 63;
    float s = 0.f;
#pragma unroll 4
    for (int t = 0; t < 64; t++) s += Ls[64 + rr][t] * Xs[t][cc];
    Xs[rr][64 + cc] = s;
  }
  __syncthreads();
  // X21 = -X22 * T
  for (int e = tid; e < 64 * 64; e += 256) {
    int rr = e >> 6, cc = e & 63;
    float s = 0.f;
#pragma unroll 4
    for (int t = 0; t < 64; t++) s += Xs[64 + rr][64 + t] * Xs[t][64 + cc];
    Xs[64 + rr][cc] = -s;
  }
  __syncthreads();
  // zero temp quadrant so Xinv is proper lower-tri inverse
  for (int e = tid; e < 64 * 64; e += 256) {
    int rr = e >> 6, cc = e & 63;
    Xs[rr][64 + cc] = 0.f;
  }
  __syncthreads();
  // write back L (lower) and Xinv (full)
  for (int e = tid; e < NSB * NSB; e += 256) {
    int rr = e >> 7, cc = e & 127;
    if (cc <= rr) M_[(size_t)(b0 + rr) * NQ2 + b0 + cc] = Ls[rr][cc];
    Xinv[e] = Xs[rr][cc];
  }
}

// ======== Cholesky panel as GEMM: L21 = A21 * Xinv^T  (in place) ========
__global__ __launch_bounds__(256) void chol_panel128_kernel(float* __restrict__ M_,
                                                            const float* __restrict__ Xinv,
                                                            int k) {
  int kc = k * NSB;
  int rb0 = kc + NSB + blockIdx.x * 128;
  __shared__ float As[16][128];
  __shared__ float Bs[16][128];
  int tid = threadIdx.x;
  int tx = tid & 15, ty = tid >> 4;
  int sr = tid >> 1, ks = (tid & 1) * 8;

  const float* ap = M_ + (size_t)(rb0 + sr) * NQ2 + kc + ks;
  const float* bp = Xinv + sr * 128 + ks;
  float4 a0 = *(const float4*)(ap), a1 = *(const float4*)(ap + 4);
  float4 b0 = *(const float4*)(bp), b1 = *(const float4*)(bp + 4);

  float acc[8][8] = {{0.f}};
  for (int k0 = 0; k0 < 128; k0 += 16) {
    __syncthreads();
    As[ks + 0][sr] = a0.x; As[ks + 1][sr] = a0.y; As[ks + 2][sr] = a0.z; As[ks + 3][sr] = a0.w;
    As[ks + 4][sr] = a1.x; As[ks + 5][sr] = a1.y; As[ks + 6][sr] = a1.z; As[ks + 7][sr] = a1.w;
    Bs[ks + 0][sr] = b0.x; Bs[ks + 1][sr] = b0.y; Bs[ks + 2][sr] = b0.z; Bs[ks + 3][sr] = b0.w;
    Bs[ks + 4][sr] = b1.x; Bs[ks + 5][sr] = b1.y; Bs[ks + 6][sr] = b1.z; Bs[ks + 7][sr] = b1.w;
    __syncthreads();
    if (k0 + 16 < 128) {
      const float* q = ap + k0 + 16;
      a0 = *(const float4*)(q); a1 = *(const float4*)(q + 4);
      q = bp + k0 + 16;
      b0 = *(const float4*)(q); b1 = *(const float4*)(q + 4);
    }
#pragma unroll
    for (int kk = 0; kk < 16; kk++) {
      float4 aL = *(const float4*)&As[kk][ty * 4];
      float4 aH = *(const float4*)&As[kk][64 + ty * 4];
      float4 bL = *(const float4*)&Bs[kk][tx * 4];
      float4 bH = *(const float4*)&Bs[kk][64 + tx * 4];
      float aa[8] = {aL.x, aL.y, aL.z, aL.w, aH.x, aH.y, aH.z, aH.w};
      float bb[8] = {bL.x, bL.y, bL.z, bL.w, bH.x, bH.y, bH.z, bH.w};
#pragma unroll
      for (int i = 0; i < 8; i++)
#pragma unroll
        for (int j = 0; j < 8; j++) acc[i][j] = fmaf(aa[i], bb[j], acc[i][j]);
    }
  }
#pragma unroll
  for (int ii = 0; ii < 8; ii++) {
    int gi = rb0 + ((ii >> 2) * 64) + ty * 4 + (ii & 3);
#pragma unroll
    for (int half = 0; half < 2; half++) {
      int gj0 = kc + half * 64 + tx * 4;
      float4 o;
      o.x = acc[ii][half * 4 + 0]; o.y = acc[ii][half * 4 + 1];
      o.z = acc[ii][half * 4 + 2]; o.w = acc[ii][half * 4 + 3];
      *(float4*)&M_[(size_t)gi * NQ2 + gj0] = o;
    }
  }
}

// ======== Cholesky trailing: C -= L21 L21^T, 128-tiles, K=128 ========
__global__ __launch_bounds__(256) void chol_trail128_kernel(float* __restrict__ M_, int k) {
  int L = blockIdx.x;
  int bi = (int)((sqrtf(8.0f * (float)L + 1.0f) - 1.0f) * 0.5f);
  while ((bi + 1) * (bi + 2) / 2 <= L) bi++;
  while (bi * (bi + 1) / 2 > L) bi--;
  int bj = L - bi * (bi + 1) / 2;
  int row0 = (k + 1 + bi) * NSB, col0 = (k + 1 + bj) * NSB, kc = k * NSB;

  __shared__ float As[16][128];
  __shared__ float Bs[16][128];
  int tid = threadIdx.x;
  int tx = tid & 15, ty = tid >> 4;
  int sr = tid >> 1, ks = (tid & 1) * 8;

  const float* ap = M_ + (size_t)(row0 + sr) * NQ2 + kc + ks;
  const float* bp = M_ + (size_t)(col0 + sr) * NQ2 + kc + ks;
  float4 a0 = *(const float4*)(ap), a1 = *(const float4*)(ap + 4);
  float4 b0 = *(const float4*)(bp), b1 = *(const float4*)(bp + 4);

  float acc[8][8] = {{0.f}};
  for (int k0 = 0; k0 < 128; k0 += 16) {
    __syncthreads();
    As[ks + 0][sr] = a0.x; As[ks + 1][sr] = a0.y; As[ks + 2][sr] = a0.z; As[ks + 3][sr] = a0.w;
    As[ks + 4][sr] = a1.x; As[ks + 5][sr] = a1.y; As[ks + 6][sr] = a1.z; As[ks + 7][sr] = a1.w;
    Bs[ks + 0][sr] = b0.x; Bs[ks + 1][sr] = b0.y; Bs[ks + 2][sr] = b0.z; Bs[ks + 3][sr] = b0.w;
    Bs[ks + 4][sr] = b1.x; Bs[ks + 5][sr] = b1.y; Bs[ks + 6][sr] = b1.z; Bs[ks + 7][sr] = b1.w;
    __syncthreads();
    if (k0 + 16 < 128) {
      const float* q = ap + k0 + 16;
      a0 = *(const float4*)(q); a1 = *(const float4*)(q + 4);
      q = bp + k0 + 16;
      b0 = *(const float4*)(q); b1 = *(const float4*)(q + 4);
    }
#pragma unroll
    for (int kk = 0; kk < 16; kk++) {
      float4 aL = *(const float4*)&As[kk][ty * 4];
      float4 aH = *(const float4*)&As[kk][64 + ty * 4];
      float4 bL = *(const float4*)&Bs[kk][tx * 4];
      float4 bH = *(const float4*)&Bs[kk][64 + tx * 4];
      float aa[8] = {aL.x, aL.y, aL.z, aL.w, aH.x, aH.y, aH.z, aH.w};
      float bb[8] = {bL.x, bL.y, bL.z, bL.w, bH.x, bH.y, bH.z, bH.w};
#pragma unroll
      for (int i = 0; i < 8; i++)
#pragma unroll
        for (int j = 0; j < 8; j++) acc[i][j] = fmaf(aa[i], bb[j], acc[i][j]);
    }
  }
#pragma unroll
  for (int ii = 0; ii < 8; ii++) {
    int gi = row0 + ((ii >> 2) * 64) + ty * 4 + (ii & 3);
#pragma unroll
    for (int half = 0; half < 2; half++) {
      int gj0 = col0 + half * 64 + tx * 4;
      float* cp = &M_[(size_t)gi * NQ2 + gj0];
      float4 v = *(const float4*)cp;
      v.x -= acc[ii][half * 4 + 0]; v.y -= acc[ii][half * 4 + 1];
      v.z -= acc[ii][half * 4 + 2]; v.w -= acc[ii][half * 4 + 3];
      *(float4*)cp = v;
    }
  }
}

// ---------------- blocked forward substitution (readlane serial chain) ----------------
template <int MODE>
__global__ __launch_bounds__(1024) void fwd_solve_kernel(const float* __restrict__ M_,
                                                         const float* __restrict__ rhs,
                                                         const float* __restrict__ invlam,
                                                         float* __restrict__ out) {
  __shared__ float partial[NQ2];
  __shared__ float il[NQ2];
  __shared__ float tile[NB][NB + 1];
  __shared__ float vblk[NB];
  int tid = threadIdx.x;
  int rquad = tid >> 2;
  int l4 = tid & 3;
  for (int i = tid; i < NQ2; i += 1024) {
    partial[i] = rhs[i];
    if (MODE == 0) il[i] = invlam[i];
  }
  __syncthreads();
  for (int b = 0; b < NBLK; b++) {
    int b0 = b * NB;
    for (int e = tid; e < NB * NB; e += 1024) {
      int rr = e >> 6, cc = e & 63;
      tile[rr][cc] = M_[(size_t)(b0 + rr) * NQ2 + b0 + cc];
    }
    __syncthreads();
    if (tid < 64) {
      int l = tid;
      float creg = partial[b0 + l];
      float ilreg = (MODE == 0) ? il[b0 + l] : 0.f;
      float dinv = (MODE == 1) ? (1.0f / tile[l][l]) : 0.f;
      float acc = 0.f;
      float wfin = 0.f;
#pragma unroll
      for (int i = 0; i < NB; i++) {
        float cand;
        if (MODE == 0) cand = fmaxf(creg - acc * ilreg, 0.f);
        else           cand = (creg - acc) * dinv;
        float wi = readlane_f(cand, i);
        acc = fmaf(tile[l][i], wi, acc);
        if (l == i) wfin = wi;
      }
      vblk[l] = wfin;
      out[b0 + l] = wfin;
    }
    __syncthreads();
    float4 v0 = *(const float4*)(&vblk[l4 * 16]);
    float4 v1 = *(const float4*)(&vblk[l4 * 16 + 4]);
    float4 v2 = *(const float4*)(&vblk[l4 * 16 + 8]);
    float4 v3 = *(const float4*)(&vblk[l4 * 16 + 12]);
    for (int base = b0 + NB; base < NQ2; base += 512) {
      int row0 = base + rquad;
      int row1 = row0 + 256;
      float acc0 = 0.f, acc1 = 0.f;
      if (row0 < NQ2) {
        const float* mr = M_ + (size_t)row0 * NQ2 + b0 + l4 * 16;
        float4 m0 = *(const float4*)(mr);
        float4 m1 = *(const float4*)(mr + 4);
        float4 m2 = *(const float4*)(mr + 8);
        float4 m3 = *(const float4*)(mr + 12);
        acc0 = m0.x * v0.x + m0.y * v0.y + m0.z * v0.z + m0.w * v0.w
             + m1.x * v1.x + m1.y * v1.y + m1.z * v1.z + m1.w * v1.w
             + m2.x * v2.x + m2.y * v2.y + m2.z * v2.z + m2.w * v2.w
             + m3.x * v3.x + m3.y * v3.y + m3.z * v3.z + m3.w * v3.w;
      }
      if (row1 < NQ2) {
        const float* mr = M_ + (size_t)row1 * NQ2 + b0 + l4 * 16;
        float4 m0 = *(const float4*)(mr);
        float4 m1 = *(const float4*)(mr + 4);
        float4 m2 = *(const float4*)(mr + 8);
        float4 m3 = *(const float4*)(mr + 12);
        acc1 = m0.x * v0.x + m0.y * v0.y + m0.z * v0.z + m0.w * v0.w
             + m1.x * v1.x + m1.y * v1.y + m1.z * v1.z + m1.w * v1.w
             + m2.x * v2.x + m2.y * v2.y + m2.z * v2.z + m2.w * v2.w
             + m3.x * v3.x + m3.y * v3.y + m3.z * v3.z + m3.w * v3.w;
      }
      acc0 += __shfl_xor(acc0, 1);
      acc0 += __shfl_xor(acc0, 2);
      acc1 += __shfl_xor(acc1, 1);
      acc1 += __shfl_xor(acc1, 2);
      if (l4 == 0) {
        if (row0 < NQ2) {
          if (MODE == 0) partial[row0] -= acc0 * il[row0];
          else           partial[row0] -= acc0;
        }
        if (row1 < NQ2) {
          if (MODE == 0) partial[row1] -= acc1 * il[row1];
          else           partial[row1] -= acc1;
        }
      }
    }
    __syncthreads();
  }
}

// ---------------- blocked backward substitution: L^T z = y ----------------
__global__ __launch_bounds__(1024) void bwd_solve_kernel(const float* __restrict__ M_,
                                                         const float* __restrict__ rhs,
                                                         float* __restrict__ out) {
  __shared__ float partial[NQ2];
  __shared__ float tile[NB][NB + 1];
  __shared__ float vblk[NB];
  int tid = threadIdx.x;
  for (int i = tid; i < NQ2; i += 1024) partial[i] = rhs[i];
  __syncthreads();
  for (int b = NBLK - 1; b >= 0; b--) {
    int b0 = b * NB;
    for (int e = tid; e < NB * NB; e += 1024) {
      int rr = e >> 6, cc = e & 63;
      tile[cc][rr] = M_[(size_t)(b0 + rr) * NQ2 + b0 + cc];
    }
    __syncthreads();
    if (tid < 64) {
      int l = tid;
      float creg = partial[b0 + l];
      float dinv = 1.0f / tile[l][l];
      float acc = 0.f;
      float zfin = 0.f;
#pragma unroll
      for (int i = NB - 1; i >= 0; i--) {
        float cand = (creg - acc) * dinv;
        float zi = readlane_f(cand, i);
        acc = fmaf(tile[l][i], zi, acc);
        if (l == i) zfin = zi;
      }
      vblk[l] = zfin;
      out[b0 + l] = zfin;
    }
    __syncthreads();
    for (int i = tid; i < b0; i += 1024) {
      float acc = 0.f;
#pragma unroll 16
      for (int l = 0; l < NB; l++) acc += M_[(size_t)(b0 + l) * NQ2 + i] * vblk[l];
      partial[i] -= acc;
    }
    __syncthreads();
  }
}

// ---------------- t = -0.5 X1^T x - X2^T w ----------------
#define TCH 32
__global__ __launch_bounds__(256) void t_partial_kernel(const float* __restrict__ X,
                                                        const float* __restrict__ x,
                                                        const float* __restrict__ w,
                                                        float* __restrict__ tpart) {
  int k4 = (blockIdx.x * 256 + threadIdx.x) * 4;
  int chunk = blockIdx.y;
  int i0 = chunk * (NT / TCH);
  float4 acc = {0.f, 0.f, 0.f, 0.f};
  for (int i = i0; i < i0 + NT / TCH; i++) {
    float cf = (i < NQ2) ? (-0.5f * x[i]) : (-w[i - NQ2]);
    float4 xv = *(const float4*)(X + (size_t)i * NT + k4);
    acc.x += cf * xv.x; acc.y += cf * xv.y; acc.z += cf * xv.z; acc.w += cf * xv.w;
  }
  *(float4*)(tpart + (size_t)chunk * NT + k4) = acc;
}

__global__ __launch_bounds__(256) void t_reduce_kernel(const float* __restrict__ tpart,
                                                       float* __restrict__ t) {
  int k = blockIdx.x * 256 + threadIdx.x;
  float s = 0.f;
#pragma unroll 8
  for (int ch = 0; ch < TCH; ch++) s += tpart[(size_t)ch * NT + k];
  t[k] = s;
}

// -------- r = X1 t - 0.5 Y1 x - U w - 0.5 eps x --------
__global__ __launch_bounds__(256) void r_kernel(const float* __restrict__ X,
                                                const float* __restrict__ Y1,
                                                const float* __restrict__ U,
                                                const float* __restrict__ t,
                                                const float* __restrict__ x,
                                                const float* __restrict__ w,
                                                float* __restrict__ r) {
  int row = blockIdx.x;
  float s1 = 0.f, s2 = 0.f, s3 = 0.f;
  const float* xr = X + (size_t)row * NT;
  for (int k = threadIdx.x * 4; k < NT; k += 1024) {
    float4 a = *(const float4*)(xr + k);
    float4 b = *(const float4*)(t + k);
    s1 += a.x * b.x + a.y * b.y + a.z * b.z + a.w * b.w;
  }
  const float* yr = Y1 + (size_t)row * NQ2;
  const float* ur = U + (size_t)row * NQ2;
  for (int k = threadIdx.x * 4; k < NQ2; k += 1024) {
    float4 a = *(const float4*)(yr + k);
    float4 b = *(const float4*)(x + k);
    s2 += a.x * b.x + a.y * b.y + a.z * b.z + a.w * b.w;
    float4 c2 = *(const float4*)(ur + k);
    float4 d2 = *(const float4*)(w + k);
    s3 += c2.x * d2.x + c2.y * d2.y + c2.z * d2.z + c2.w * d2.w;
  }
  float v = s1 - 0.5f * s2 - s3;
  float tot = block_reduce_256(v);
  if (threadIdx.x == 0) r[row] = tot - 0.5f * FEPS * x[row];
}

// ---------------- IR: res = r - (XP pz1 + eps z) ----------------
__global__ __launch_bounds__(256) void pz2_res_kernel(const float* __restrict__ XP,
                                                      const float* __restrict__ pz1,
                                                      const float* __restrict__ z,
                                                      const float* __restrict__ r,
                                                      float* __restrict__ res) {
  int row = blockIdx.x;
  float s = 0.f;
  const float* xr = XP + (size_t)row * NQ2;
  for (int k = threadIdx.x * 4; k < NQ2; k += 1024) {
    float4 a = *(const float4*)(xr + k);
    float4 b = *(const float4*)(pz1 + k);
    s += a.x * b.x + a.y * b.y + a.z * b.z + a.w * b.w;
  }
  float tot = block_reduce_256(s);
  if (threadIdx.x == 0) res[row] = r[row] - (tot + FEPS * z[row]);
}

__global__ __launch_bounds__(256) void axpy_kernel(float* __restrict__ z,
                                                   const float* __restrict__ dz) {
  int i = blockIdx.x * 256 + threadIdx.x;
  z[i] += dz[i];
}

// ---------------- out = z + B2 u ----------------
__global__ __launch_bounds__(256) void out_kernel(const float* __restrict__ z,
                                                  const float* __restrict__ B2,
                                                  const float* __restrict__ u,
                                                  float* __restrict__ out) {
  int i = blockIdx.x * 256 + threadIdx.x;
  float s = 0.f;
#pragma unroll
  for (int j = 0; j < NUU; j++) s += B2[(size_t)i * NUU + j] * u[j];
  out[i] = z[i] + s;
}

extern "C" void kernel_launch(void* const* d_in, const int* in_sizes, int n_in,
                              void* d_out, int out_size, void* d_ws, size_t ws_size,
                              hipStream_t stream) {
  (void)in_sizes; (void)n_in; (void)out_size; (void)ws_size;
  const float* x   = (const float*)d_in[1];
  const float* u   = (const float*)d_in[2];
  const float* X   = (const float*)d_in[3];
  const float* U   = (const float*)d_in[4];
  const float* Y1  = (const float*)d_in[5];
  const float* XP  = (const float*)d_in[6];
  const float* B2  = (const float*)d_in[7];
  const float* D12 = (const float*)d_in[8];
  float* out = (float*)d_out;

  float* ws     = (float*)d_ws;
  float* M      = ws;                           // 2048*2048
  float* vecs   = ws + (size_t)NQ2 * NQ2;
  float* invlam = vecs;
  float* c      = vecs + 2048;
  float* w      = vecs + 4096;
  float* r      = vecs + 6144;
  float* y      = vecs + 8192;
  float* z      = vecs + 10240;
  float* dz     = vecs + 12288;
  float* res    = vecs + 14336;
  float* t      = vecs + 16384;                 // 4096 (also pz1)
  float* tpart  = vecs + 20480;                 // 32*4096 (also gpart)
  float* gpart  = tpart;
  float* Xinv   = vecs + 20480 + 32 * 4096;     // 128*128

  int nsyrk = (NQ2 / 128) * (NQ2 / 128 + 1) / 2;  // 136
  dim3 gdim(NQ2 / 256, GCH);

  // lam, c = (U^T x)/lam + D12 u
  lam_kernel<<<NQ2, 256, 0, stream>>>(X, invlam);
  tgemv_part_kernel<<<gdim, 256, 0, stream>>>(U, x, gpart);
  finish_kernel<0><<<NQ2 / 256, 256, 0, stream>>>(gpart, invlam, D12, u, c);

  // H22 into M (MFMA bf16-split), then relu-triangular solve for w
  syrk_mfma_kernel<<<nsyrk, 256, 0, stream>>>(X + (size_t)NQ2 * NT, NT, NT, M, 0.0f);
  fwd_solve_kernel<0><<<1, 1024, 0, stream>>>(M, c, invlam, w);

  // r
  dim3 tg(4, TCH);
  t_partial_kernel<<<tg, 256, 0, stream>>>(X, x, w, tpart);
  t_reduce_kernel<<<NT / 256, 256, 0, stream>>>(tpart, t);
  r_kernel<<<NQ2, 256, 0, stream>>>(X, Y1, U, t, x, w, r);
  tgemv_part_kernel<<<gdim, 256, 0, stream>>>(Y1, x, gpart);
  finish_kernel<1><<<NQ2 / 256, 256, 0, stream>>>(gpart, invlam, D12, u, r);

  // P = XP XP^T + eps I into M (MFMA), then blocked Cholesky (NSB=128)
  syrk_mfma_kernel<<<nsyrk, 256, 0, stream>>>(XP, NQ2, NQ2, M, FEPS);
  for (int k = 0; k < NSBLK; k++) {
    chol_diag128_kernel<<<1, 256, 0, stream>>>(M, Xinv, k);
    int rows_below = NQ2 - (k + 1) * NSB;
    if (rows_below > 0) {
      chol_panel128_kernel<<<rows_below / 128, 256, 0, stream>>>(M, Xinv, k);
      int m = NSBLK - 1 - k;
      chol_trail128_kernel<<<m * (m + 1) / 2, 256, 0, stream>>>(M, k);
    }
  }

  // solve P z = r
  fwd_solve_kernel<1><<<1, 1024, 0, stream>>>(M, r, invlam, y);
  bwd_solve_kernel<<<1, 1024, 0, stream>>>(M, y, z);

  // 2 steps of iterative refinement
  for (int it = 0; it < 2; it++) {
    tgemv_part_kernel<<<gdim, 256, 0, stream>>>(XP, z, gpart);
    finish_kernel<2><<<NQ2 / 256, 256, 0, stream>>>(gpart, invlam, D12, u, t);
    pz2_res_kernel<<<NQ2, 256, 0, stream>>>(XP, t, z, r, res);
    fwd_solve_kernel<1><<<1, 1024, 0, stream>>>(M, res, invlam, y);
    bwd_solve_kernel<<<1, 1024, 0, stream>>>(M, y, dz);
    axpy_kernel<<<NQ2 / 256, 256, 0, stream>>>(z, dz);
  }

  out_kernel<<<NQ2 / 256, 256, 0, stream>>>(z, B2, u, out);
}

// Round 7
// 7177.834 us; speedup vs baseline: 1.0161x; 1.0161x over previous
//
#include <hip/hip_runtime.h>
#include <math.h>

#define NQ2 2048      // nx = nq = 2048
#define NT  4096      // nx + nq
#define NUU 16
#define FEPS 0.01f
#define NB  64
#define NBLK 32       // 2048 / 64 (solve blocking)
#define NSB 128       // cholesky super-block
#define NSBLK 16      // 2048 / 128
#define GCH 16        // split-K chunks for transposed GEMVs

typedef __attribute__((ext_vector_type(8))) short short8;
typedef __attribute__((ext_vector_type(4))) float floatx4;

__device__ __forceinline__ float readlane_f(float v, int lane) {
  return __int_as_float(__builtin_amdgcn_readlane(__float_as_int(v), lane));
}

__device__ __forceinline__ unsigned short f2bf(float x) {
  unsigned u = __float_as_uint(x);
  unsigned r = u + 0x7FFFu + ((u >> 16) & 1u);
  return (unsigned short)(r >> 16);
}
__device__ __forceinline__ float bf2f(unsigned short h) {
  return __uint_as_float(((unsigned)h) << 16);
}

// ---------------- reductions ----------------
__device__ __forceinline__ float wave_reduce(float v) {
#pragma unroll
  for (int off = 32; off > 0; off >>= 1) v += __shfl_down(v, off, 64);
  return v;
}

__device__ __forceinline__ float block_reduce_256(float v) {
  __shared__ float sm[4];
  v = wave_reduce(v);
  if ((threadIdx.x & 63) == 0) sm[threadIdx.x >> 6] = v;
  __syncthreads();
  return (threadIdx.x == 0) ? (sm[0] + sm[1] + sm[2] + sm[3]) : 0.0f;
}

// ---------------- lam: inv(0.5*(||X2 row||^2 + eps)) ----------------
__global__ __launch_bounds__(256) void lam_kernel(const float* __restrict__ X,
                                                  float* __restrict__ invlam) {
  int row = blockIdx.x;
  const float* xr = X + (size_t)(NQ2 + row) * NT;
  float s = 0.f;
  for (int k = threadIdx.x * 4; k < NT; k += 1024) {
    float4 v = *(const float4*)(xr + k);
    s += v.x * v.x + v.y * v.y + v.z * v.z + v.w * v.w;
  }
  float tot = block_reduce_256(s);
  if (threadIdx.x == 0) invlam[row] = 1.0f / (0.5f * (tot + FEPS));
}

// ---------------- split-K transposed GEMV ----------------
__global__ __launch_bounds__(256) void tgemv_part_kernel(const float* __restrict__ A,
                                                         const float* __restrict__ v,
                                                         float* __restrict__ part) {
  int col = blockIdx.x * 256 + threadIdx.x;
  int ch = blockIdx.y;
  int i0 = ch * (NQ2 / GCH), i1 = i0 + NQ2 / GCH;
  float s = 0.f;
#pragma unroll 4
  for (int i = i0; i < i1; i++) s = fmaf(A[(size_t)i * NQ2 + col], v[i], s);
  part[(size_t)ch * NQ2 + col] = s;
}

// FM 0: c = sum*invlam + D12 u   FM 1: r += 0.5*sum   FM 2: dst = sum
template <int FM>
__global__ __launch_bounds__(256) void finish_kernel(const float* __restrict__ part,
                                                     const float* __restrict__ invlam,
                                                     const float* __restrict__ D12,
                                                     const float* __restrict__ u,
                                                     float* __restrict__ dst) {
  int col = blockIdx.x * 256 + threadIdx.x;
  float s = 0.f;
#pragma unroll
  for (int ch = 0; ch < GCH; ch++) s += part[(size_t)ch * NQ2 + col];
  if (FM == 0) {
    float d = 0.f;
#pragma unroll
    for (int j = 0; j < NUU; j++) d += D12[(size_t)col * NUU + j] * u[j];
    dst[col] = s * invlam[col] + d;
  } else if (FM == 1) {
    dst[col] += 0.5f * s;
  } else {
    dst[col] = s;
  }
}

// ============ MFMA SYRK (bf16 hi/lo split): C = A A^T (+eps diag), lower 128-tiles ====
__global__ __launch_bounds__(256) void syrk_mfma_kernel(const float* __restrict__ A,
                                                        int lda, int K,
                                                        float* __restrict__ C, float eps) {
  int L = blockIdx.x;
  int bi = (int)((sqrtf(8.0f * (float)L + 1.0f) - 1.0f) * 0.5f);
  while ((bi + 1) * (bi + 2) / 2 <= L) bi++;
  while (bi * (bi + 1) / 2 > L) bi--;
  int bj = L - bi * (bi + 1) / 2;
  int row0 = bi * 128, col0 = bj * 128;

  __shared__ __align__(16) short Ah[4096], Al[4096], Bh[4096], Bl[4096];

  int tid = threadIdx.x;
  int l = tid & 63;
  int w = tid >> 6;
  int wr = w >> 1, wc = w & 1;

  int g0 = tid, g1 = tid + 256;
  int ar0 = (g0 >> 6) * 16 + (g0 & 15), ak0 = ((g0 >> 4) & 3) * 8;
  int ar1 = (g1 >> 6) * 16 + (g1 & 15), ak1 = ((g1 >> 4) & 3) * 8;

  const float* pa0 = A + (size_t)(row0 + ar0) * lda + ak0;
  const float* pa1 = A + (size_t)(row0 + ar1) * lda + ak1;
  const float* pb0 = A + (size_t)(col0 + ar0) * lda + ak0;
  const float* pb1 = A + (size_t)(col0 + ar1) * lda + ak1;

  floatx4 acc[4][4];
#pragma unroll
  for (int m = 0; m < 4; m++)
#pragma unroll
    for (int n = 0; n < 4; n++) acc[m][n] = (floatx4){0.f, 0.f, 0.f, 0.f};

  float xa0[8], xa1[8], xb0[8], xb1[8];
  {
    float4 t0 = *(const float4*)(pa0), t1 = *(const float4*)(pa0 + 4);
    xa0[0]=t0.x; xa0[1]=t0.y; xa0[2]=t0.z; xa0[3]=t0.w; xa0[4]=t1.x; xa0[5]=t1.y; xa0[6]=t1.z; xa0[7]=t1.w;
    t0 = *(const float4*)(pa1); t1 = *(const float4*)(pa1 + 4);
    xa1[0]=t0.x; xa1[1]=t0.y; xa1[2]=t0.z; xa1[3]=t0.w; xa1[4]=t1.x; xa1[5]=t1.y; xa1[6]=t1.z; xa1[7]=t1.w;
    t0 = *(const float4*)(pb0); t1 = *(const float4*)(pb0 + 4);
    xb0[0]=t0.x; xb0[1]=t0.y; xb0[2]=t0.z; xb0[3]=t0.w; xb0[4]=t1.x; xb0[5]=t1.y; xb0[6]=t1.z; xb0[7]=t1.w;
    t0 = *(const float4*)(pb1); t1 = *(const float4*)(pb1 + 4);
    xb1[0]=t0.x; xb1[1]=t0.y; xb1[2]=t0.z; xb1[3]=t0.w; xb1[4]=t1.x; xb1[5]=t1.y; xb1[6]=t1.z; xb1[7]=t1.w;
  }

  for (int k0 = 0; k0 < K; k0 += 32) {
    __syncthreads();
    {
      short8 h, lo;
#pragma unroll
      for (int j = 0; j < 8; j++) { unsigned short hb = f2bf(xa0[j]); h[j] = (short)hb; lo[j] = (short)f2bf(xa0[j] - bf2f(hb)); }
      *(short8*)&Ah[g0 * 8] = h; *(short8*)&Al[g0 * 8] = lo;
#pragma unroll
      for (int j = 0; j < 8; j++) { unsigned short hb = f2bf(xa1[j]); h[j] = (short)hb; lo[j] = (short)f2bf(xa1[j] - bf2f(hb)); }
      *(short8*)&Ah[g1 * 8] = h; *(short8*)&Al[g1 * 8] = lo;
#pragma unroll
      for (int j = 0; j < 8; j++) { unsigned short hb = f2bf(xb0[j]); h[j] = (short)hb; lo[j] = (short)f2bf(xb0[j] - bf2f(hb)); }
      *(short8*)&Bh[g0 * 8] = h; *(short8*)&Bl[g0 * 8] = lo;
#pragma unroll
      for (int j = 0; j < 8; j++) { unsigned short hb = f2bf(xb1[j]); h[j] = (short)hb; lo[j] = (short)f2bf(xb1[j] - bf2f(hb)); }
      *(short8*)&Bh[g1 * 8] = h; *(short8*)&Bl[g1 * 8] = lo;
    }
    __syncthreads();
    if (k0 + 32 < K) {
      const float* q = pa0 + k0 + 32;
      float4 t0 = *(const float4*)(q), t1 = *(const float4*)(q + 4);
      xa0[0]=t0.x; xa0[1]=t0.y; xa0[2]=t0.z; xa0[3]=t0.w; xa0[4]=t1.x; xa0[5]=t1.y; xa0[6]=t1.z; xa0[7]=t1.w;
      q = pa1 + k0 + 32; t0 = *(const float4*)(q); t1 = *(const float4*)(q + 4);
      xa1[0]=t0.x; xa1[1]=t0.y; xa1[2]=t0.z; xa1[3]=t0.w; xa1[4]=t1.x; xa1[5]=t1.y; xa1[6]=t1.z; xa1[7]=t1.w;
      q = pb0 + k0 + 32; t0 = *(const float4*)(q); t1 = *(const float4*)(q + 4);
      xb0[0]=t0.x; xb0[1]=t0.y; xb0[2]=t0.z; xb0[3]=t0.w; xb0[4]=t1.x; xb0[5]=t1.y; xb0[6]=t1.z; xb0[7]=t1.w;
      q = pb1 + k0 + 32; t0 = *(const float4*)(q); t1 = *(const float4*)(q + 4);
      xb1[0]=t0.x; xb1[1]=t0.y; xb1[2]=t0.z; xb1[3]=t0.w; xb1[4]=t1.x; xb1[5]=t1.y; xb1[6]=t1.z; xb1[7]=t1.w;
    }
    short8 amh[4], aml[4], bnh[4], bnl[4];
#pragma unroll
    for (int m = 0; m < 4; m++) {
      int ga = ((wr * 4 + m) * 64 + l) * 8;
      amh[m] = *(const short8*)&Ah[ga];
      aml[m] = *(const short8*)&Al[ga];
    }
#pragma unroll
    for (int n = 0; n < 4; n++) {
      int gb = ((wc * 4 + n) * 64 + l) * 8;
      bnh[n] = *(const short8*)&Bh[gb];
      bnl[n] = *(const short8*)&Bl[gb];
    }
#pragma unroll
    for (int m = 0; m < 4; m++)
#pragma unroll
      for (int n = 0; n < 4; n++) {
        acc[m][n] = __builtin_amdgcn_mfma_f32_16x16x32_bf16(amh[m], bnh[n], acc[m][n], 0, 0, 0);
        acc[m][n] = __builtin_amdgcn_mfma_f32_16x16x32_bf16(amh[m], bnl[n], acc[m][n], 0, 0, 0);
        acc[m][n] = __builtin_amdgcn_mfma_f32_16x16x32_bf16(aml[m], bnh[n], acc[m][n], 0, 0, 0);
      }
  }

  int lr = (l >> 4) * 4;
  int lc = l & 15;
#pragma unroll
  for (int m = 0; m < 4; m++)
#pragma unroll
    for (int n = 0; n < 4; n++)
#pragma unroll
      for (int r = 0; r < 4; r++) {
        int gi = row0 + wr * 64 + m * 16 + lr + r;
        int gj = col0 + wc * 64 + n * 16 + lc;
        float v = acc[m][n][r];
        if (gi == gj) v += eps;
        C[(size_t)gi * NQ2 + gj] = v;
      }
}

// ======== Cholesky diag: LDL-style factor (1 barrier/step) + X = inv(L) ========
__global__ __launch_bounds__(256) void chol_diag128_kernel(float* __restrict__ M_,
                                                           float* __restrict__ Xinv, int k) {
  __shared__ float Ls[NSB][NSB + 1];
  __shared__ float Xs[NSB][NSB + 1];
  __shared__ float rsv[NSB];
  int b0 = k * NSB;
  int tid = threadIdx.x;
  for (int e = tid; e < NSB * NSB; e += 256) {
    int rr = e >> 7, cc = e & 127;
    Ls[rr][cc] = M_[(size_t)(b0 + rr) * NQ2 + b0 + cc];
    Xs[rr][cc] = 0.f;
  }
  __syncthreads();
  // LDL-style right-looking factor: column-parallel rank-1, ONE barrier per step
  int t2 = tid >> 1, par = tid & 1;
#pragma unroll 1
  for (int jj = 0; jj < NSB; jj++) {
    float d = fmaxf(Ls[jj][jj], 1e-20f);
    float dinv = 1.0f / d;
    if (tid == 0) rsv[jj] = rsqrtf(d);
    int cc = jj + 1 + t2;
    if (cc < NSB) {
      float lc = Ls[cc][jj] * dinv;
#pragma unroll 4
      for (int r = cc + par; r < NSB; r += 2)
        Ls[r][cc] = fmaf(-Ls[r][jj], lc, Ls[r][cc]);
    }
    __syncthreads();
  }
  // normalize raw columns to Cholesky L: L[r][j] = raw[r][j] * rsqrt(d_j)
  for (int e = tid; e < NSB * NSB; e += 256) {
    int rr = e >> 7, cc = e & 127;
    if (cc <= rr) Ls[rr][cc] *= rsv[cc];
  }
  __syncthreads();
  // blocked inverse: X11=inv(L11), X22=inv(L22) via lane-paired column chains
  {
    int half = tid >> 7;        // 0 -> L11, 1 -> L22
    int tt2 = tid & 127;
    int col = tt2 >> 1, p = tt2 & 1;
    int o = half * 64;
    float diaginv = 1.0f / Ls[o + col][o + col];
    if (p == 0) Xs[o + col][o + col] = diaginv;
#pragma unroll 1
    for (int i = col + 1; i < 64; i++) {
      float s = 0.f;
      for (int t = col + p; t < i; t += 2) s += Ls[o + i][o + t] * Xs[o + t][o + col];
      s += __shfl_xor(s, 1);
      float xi = -s / Ls[o + i][o + i];
      if (p == 0) Xs[o + i][o + col] = xi;
    }
  }
  __syncthreads();
  // T = L21 * X11  -> temp in upper quadrant Xs[0:64][64:128]
  for (int e = tid; e < 64 * 64; e += 256) {
    int rr = e >> 6, cc = e & 63;
    float s = 0.f;
#pragma unroll 8
    for (int t = 0; t < 64; t++) s += Ls[64 + rr][t] * Xs[t][cc];
    Xs[rr][64 + cc] = s;
  }
  __syncthreads();
  // X21 = -X22 * T
  for (int e = tid; e < 64 * 64; e += 256) {
    int rr = e >> 6, cc = e & 63;
    float s = 0.f;
#pragma unroll 8
    for (int t = 0; t < 64; t++) s += Xs[64 + rr][64 + t] * Xs[t][64 + cc];
    Xs[64 + rr][cc] = -s;
  }
  __syncthreads();
  // zero temp quadrant
  for (int e = tid; e < 64 * 64; e += 256) {
    int rr = e >> 6, cc = e & 63;
    Xs[rr][64 + cc] = 0.f;
  }
  __syncthreads();
  // write back L (lower) and Xinv (full)
  for (int e = tid; e < NSB * NSB; e += 256) {
    int rr = e >> 7, cc = e & 127;
    if (cc <= rr) M_[(size_t)(b0 + rr) * NQ2 + b0 + cc] = Ls[rr][cc];
    Xinv[e] = Xs[rr][cc];
  }
}

// ======== Cholesky panel as GEMM: L21 = A21 * Xinv^T  (in place) ========
__global__ __launch_bounds__(256) void chol_panel128_kernel(float* __restrict__ M_,
                                                            const float* __restrict__ Xinv,
                                                            int k) {
  int kc = k * NSB;
  int rb0 = kc + NSB + blockIdx.x * 128;
  __shared__ float As[16][128];
  __shared__ float Bs[16][128];
  int tid = threadIdx.x;
  int tx = tid & 15, ty = tid >> 4;
  int sr = tid >> 1, ks = (tid & 1) * 8;

  const float* ap = M_ + (size_t)(rb0 + sr) * NQ2 + kc + ks;
  const float* bp = Xinv + sr * 128 + ks;
  float4 a0 = *(const float4*)(ap), a1 = *(const float4*)(ap + 4);
  float4 b0 = *(const float4*)(bp), b1 = *(const float4*)(bp + 4);

  float acc[8][8] = {{0.f}};
  for (int k0 = 0; k0 < 128; k0 += 16) {
    __syncthreads();
    As[ks + 0][sr] = a0.x; As[ks + 1][sr] = a0.y; As[ks + 2][sr] = a0.z; As[ks + 3][sr] = a0.w;
    As[ks + 4][sr] = a1.x; As[ks + 5][sr] = a1.y; As[ks + 6][sr] = a1.z; As[ks + 7][sr] = a1.w;
    Bs[ks + 0][sr] = b0.x; Bs[ks + 1][sr] = b0.y; Bs[ks + 2][sr] = b0.z; Bs[ks + 3][sr] = b0.w;
    Bs[ks + 4][sr] = b1.x; Bs[ks + 5][sr] = b1.y; Bs[ks + 6][sr] = b1.z; Bs[ks + 7][sr] = b1.w;
    __syncthreads();
    if (k0 + 16 < 128) {
      const float* q = ap + k0 + 16;
      a0 = *(const float4*)(q); a1 = *(const float4*)(q + 4);
      q = bp + k0 + 16;
      b0 = *(const float4*)(q); b1 = *(const float4*)(q + 4);
    }
#pragma unroll
    for (int kk = 0; kk < 16; kk++) {
      float4 aL = *(const float4*)&As[kk][ty * 4];
      float4 aH = *(const float4*)&As[kk][64 + ty * 4];
      float4 bL = *(const float4*)&Bs[kk][tx * 4];
      float4 bH = *(const float4*)&Bs[kk][64 + tx * 4];
      float aa[8] = {aL.x, aL.y, aL.z, aL.w, aH.x, aH.y, aH.z, aH.w};
      float bb[8] = {bL.x, bL.y, bL.z, bL.w, bH.x, bH.y, bH.z, bH.w};
#pragma unroll
      for (int i = 0; i < 8; i++)
#pragma unroll
        for (int j = 0; j < 8; j++) acc[i][j] = fmaf(aa[i], bb[j], acc[i][j]);
    }
  }
#pragma unroll
  for (int ii = 0; ii < 8; ii++) {
    int gi = rb0 + ((ii >> 2) * 64) + ty * 4 + (ii & 3);
#pragma unroll
    for (int half = 0; half < 2; half++) {
      int gj0 = kc + half * 64 + tx * 4;
      float4 o;
      o.x = acc[ii][half * 4 + 0]; o.y = acc[ii][half * 4 + 1];
      o.z = acc[ii][half * 4 + 2]; o.w = acc[ii][half * 4 + 3];
      *(float4*)&M_[(size_t)gi * NQ2 + gj0] = o;
    }
  }
}

// ======== Cholesky trailing: C -= L21 L21^T, 128-tiles, K=128 ========
__global__ __launch_bounds__(256) void chol_trail128_kernel(float* __restrict__ M_, int k) {
  int L = blockIdx.x;
  int bi = (int)((sqrtf(8.0f * (float)L + 1.0f) - 1.0f) * 0.5f);
  while ((bi + 1) * (bi + 2) / 2 <= L) bi++;
  while (bi * (bi + 1) / 2 > L) bi--;
  int bj = L - bi * (bi + 1) / 2;
  int row0 = (k + 1 + bi) * NSB, col0 = (k + 1 + bj) * NSB, kc = k * NSB;

  __shared__ float As[16][128];
  __shared__ float Bs[16][128];
  int tid = threadIdx.x;
  int tx = tid & 15, ty = tid >> 4;
  int sr = tid >> 1, ks = (tid & 1) * 8;

  const float* ap = M_ + (size_t)(row0 + sr) * NQ2 + kc + ks;
  const float* bp = M_ + (size_t)(col0 + sr) * NQ2 + kc + ks;
  float4 a0 = *(const float4*)(ap), a1 = *(const float4*)(ap + 4);
  float4 b0 = *(const float4*)(bp), b1 = *(const float4*)(bp + 4);

  float acc[8][8] = {{0.f}};
  for (int k0 = 0; k0 < 128; k0 += 16) {
    __syncthreads();
    As[ks + 0][sr] = a0.x; As[ks + 1][sr] = a0.y; As[ks + 2][sr] = a0.z; As[ks + 3][sr] = a0.w;
    As[ks + 4][sr] = a1.x; As[ks + 5][sr] = a1.y; As[ks + 6][sr] = a1.z; As[ks + 7][sr] = a1.w;
    Bs[ks + 0][sr] = b0.x; Bs[ks + 1][sr] = b0.y; Bs[ks + 2][sr] = b0.z; Bs[ks + 3][sr] = b0.w;
    Bs[ks + 4][sr] = b1.x; Bs[ks + 5][sr] = b1.y; Bs[ks + 6][sr] = b1.z; Bs[ks + 7][sr] = b1.w;
    __syncthreads();
    if (k0 + 16 < 128) {
      const float* q = ap + k0 + 16;
      a0 = *(const float4*)(q); a1 = *(const float4*)(q + 4);
      q = bp + k0 + 16;
      b0 = *(const float4*)(q); b1 = *(const float4*)(q + 4);
    }
#pragma unroll
    for (int kk = 0; kk < 16; kk++) {
      float4 aL = *(const float4*)&As[kk][ty * 4];
      float4 aH = *(const float4*)&As[kk][64 + ty * 4];
      float4 bL = *(const float4*)&Bs[kk][tx * 4];
      float4 bH = *(const float4*)&Bs[kk][64 + tx * 4];
      float aa[8] = {aL.x, aL.y, aL.z, aL.w, aH.x, aH.y, aH.z, aH.w};
      float bb[8] = {bL.x, bL.y, bL.z, bL.w, bH.x, bH.y, bH.z, bH.w};
#pragma unroll
      for (int i = 0; i < 8; i++)
#pragma unroll
        for (int j = 0; j < 8; j++) acc[i][j] = fmaf(aa[i], bb[j], acc[i][j]);
    }
  }
#pragma unroll
  for (int ii = 0; ii < 8; ii++) {
    int gi = row0 + ((ii >> 2) * 64) + ty * 4 + (ii & 3);
#pragma unroll
    for (int half = 0; half < 2; half++) {
      int gj0 = col0 + half * 64 + tx * 4;
      float* cp = &M_[(size_t)gi * NQ2 + gj0];
      float4 v = *(const float4*)cp;
      v.x -= acc[ii][half * 4 + 0]; v.y -= acc[ii][half * 4 + 1];
      v.z -= acc[ii][half * 4 + 2]; v.w -= acc[ii][half * 4 + 3];
      *(float4*)cp = v;
    }
  }
}

// -------- blocked forward substitution: 512 thr, 2 barriers/block, tile prefetch --------
// MODE 0: w_i = relu(c_i - (sum_{j<i} M[i,j] w_j) * invlam_i)
// MODE 1: y_i = (r_i - sum_{j<i} L[i,j] y_j) / L[i,i]
template <int MODE>
__global__ __launch_bounds__(512) void fwd_solve_kernel(const float* __restrict__ M_,
                                                        const float* __restrict__ rhs,
                                                        const float* __restrict__ invlam,
                                                        float* __restrict__ out) {
  __shared__ float partial[NQ2];
  __shared__ float il[NQ2];
  __shared__ float tile[2][NB][NB + 1];
  __shared__ float vblk[NB];
  int tid = threadIdx.x;
  int rquad = tid >> 2;   // 0..127
  int l4 = tid & 3;
  for (int i = tid; i < NQ2; i += 512) {
    partial[i] = rhs[i];
    if (MODE == 0) il[i] = invlam[i];
  }
  for (int e = tid; e < NB * NB; e += 512) {
    int rr = e >> 6, cc = e & 63;
    tile[0][rr][cc] = M_[(size_t)rr * NQ2 + cc];
  }
  __syncthreads();
  for (int b = 0; b < NBLK; b++) {
    int cur = b & 1;
    int b0 = b * NB;
    if (tid < 64) {
      // serial chain (wave 0)
      int l = tid;
      float creg = partial[b0 + l];
      float ilreg = (MODE == 0) ? il[b0 + l] : 0.f;
      float dinv = (MODE == 1) ? (1.0f / tile[cur][l][l]) : 0.f;
      float acc = 0.f;
      float wfin = 0.f;
#pragma unroll
      for (int i = 0; i < NB; i++) {
        float cand;
        if (MODE == 0) cand = fmaxf(creg - acc * ilreg, 0.f);
        else           cand = (creg - acc) * dinv;
        float wi = readlane_f(cand, i);
        acc = fmaf(tile[cur][l][i], wi, acc);
        if (l == i) wfin = wi;
      }
      vblk[l] = wfin;
      out[b0 + l] = wfin;
    } else if (b + 1 < NBLK) {
      // waves 1..7 prefetch next diag tile
      int b1 = b0 + NB;
      for (int e = tid - 64; e < NB * NB; e += 448) {
        int rr = e >> 6, cc = e & 63;
        tile[cur ^ 1][rr][cc] = M_[(size_t)(b1 + rr) * NQ2 + b1 + cc];
      }
    }
    __syncthreads();
    // GEMV: 4 lanes/row, 2-row unroll => 256 rows/iter
    float4 v0 = *(const float4*)(&vblk[l4 * 16]);
    float4 v1 = *(const float4*)(&vblk[l4 * 16 + 4]);
    float4 v2 = *(const float4*)(&vblk[l4 * 16 + 8]);
    float4 v3 = *(const float4*)(&vblk[l4 * 16 + 12]);
    for (int base = b0 + NB; base < NQ2; base += 256) {
      int row0 = base + rquad;
      int row1 = row0 + 128;
      float acc0 = 0.f, acc1 = 0.f;
      if (row0 < NQ2) {
        const float* mr = M_ + (size_t)row0 * NQ2 + b0 + l4 * 16;
        float4 m0 = *(const float4*)(mr);
        float4 m1 = *(const float4*)(mr + 4);
        float4 m2 = *(const float4*)(mr + 8);
        float4 m3 = *(const float4*)(mr + 12);
        acc0 = m0.x * v0.x + m0.y * v0.y + m0.z * v0.z + m0.w * v0.w
             + m1.x * v1.x + m1.y * v1.y + m1.z * v1.z + m1.w * v1.w
             + m2.x * v2.x + m2.y * v2.y + m2.z * v2.z + m2.w * v2.w
             + m3.x * v3.x + m3.y * v3.y + m3.z * v3.z + m3.w * v3.w;
      }
      if (row1 < NQ2) {
        const float* mr = M_ + (size_t)row1 * NQ2 + b0 + l4 * 16;
        float4 m0 = *(const float4*)(mr);
        float4 m1 = *(const float4*)(mr + 4);
        float4 m2 = *(const float4*)(mr + 8);
        float4 m3 = *(const float4*)(mr + 12);
        acc1 = m0.x * v0.x + m0.y * v0.y + m0.z * v0.z + m0.w * v0.w
             + m1.x * v1.x + m1.y * v1.y + m1.z * v1.z + m1.w * v1.w
             + m2.x * v2.x + m2.y * v2.y + m2.z * v2.z + m2.w * v2.w
             + m3.x * v3.x + m3.y * v3.y + m3.z * v3.z + m3.w * v3.w;
      }
      acc0 += __shfl_xor(acc0, 1);
      acc0 += __shfl_xor(acc0, 2);
      acc1 += __shfl_xor(acc1, 1);
      acc1 += __shfl_xor(acc1, 2);
      if (l4 == 0) {
        if (row0 < NQ2) {
          if (MODE == 0) partial[row0] -= acc0 * il[row0];
          else           partial[row0] -= acc0;
        }
        if (row1 < NQ2) {
          if (MODE == 0) partial[row1] -= acc1 * il[row1];
          else           partial[row1] -= acc1;
        }
      }
    }
    __syncthreads();
  }
}

// -------- blocked backward substitution: L^T z = y (512 thr, prefetch) --------
__global__ __launch_bounds__(512) void bwd_solve_kernel(const float* __restrict__ M_,
                                                        const float* __restrict__ rhs,
                                                        float* __restrict__ out) {
  __shared__ float partial[NQ2];
  __shared__ float tile[2][NB][NB + 1];  // tile[.][a][b] = L[b0+b][b0+a]
  __shared__ float vblk[NB];
  int tid = threadIdx.x;
  for (int i = tid; i < NQ2; i += 512) partial[i] = rhs[i];
  {
    int b0 = (NBLK - 1) * NB;
    for (int e = tid; e < NB * NB; e += 512) {
      int rr = e >> 6, cc = e & 63;
      tile[(NBLK - 1) & 1][cc][rr] = M_[(size_t)(b0 + rr) * NQ2 + b0 + cc];
    }
  }
  __syncthreads();
  for (int b = NBLK - 1; b >= 0; b--) {
    int cur = b & 1;
    int b0 = b * NB;
    if (tid < 64) {
      int l = tid;
      float creg = partial[b0 + l];
      float dinv = 1.0f / tile[cur][l][l];
      float acc = 0.f;
      float zfin = 0.f;
#pragma unroll
      for (int i = NB - 1; i >= 0; i--) {
        float cand = (creg - acc) * dinv;
        float zi = readlane_f(cand, i);
        acc = fmaf(tile[cur][l][i], zi, acc);
        if (l == i) zfin = zi;
      }
      vblk[l] = zfin;
      out[b0 + l] = zfin;
    } else if (b > 0) {
      int b1 = b0 - NB;
      for (int e = tid - 64; e < NB * NB; e += 448) {
        int rr = e >> 6, cc = e & 63;
        tile[cur ^ 1][cc][rr] = M_[(size_t)(b1 + rr) * NQ2 + b1 + cc];
      }
    }
    __syncthreads();
    for (int i = tid; i < b0; i += 512) {
      float acc = 0.f;
#pragma unroll 16
      for (int l = 0; l < NB; l++) acc += M_[(size_t)(b0 + l) * NQ2 + i] * vblk[l];
      partial[i] -= acc;
    }
    __syncthreads();
  }
}

// ---------------- t = -0.5 X1^T x - X2^T w ----------------
#define TCH 32
__global__ __launch_bounds__(256) void t_partial_kernel(const float* __restrict__ X,
                                                        const float* __restrict__ x,
                                                        const float* __restrict__ w,
                                                        float* __restrict__ tpart) {
  int k4 = (blockIdx.x * 256 + threadIdx.x) * 4;
  int chunk = blockIdx.y;
  int i0 = chunk * (NT / TCH);
  float4 acc = {0.f, 0.f, 0.f, 0.f};
  for (int i = i0; i < i0 + NT / TCH; i++) {
    float cf = (i < NQ2) ? (-0.5f * x[i]) : (-w[i - NQ2]);
    float4 xv = *(const float4*)(X + (size_t)i * NT + k4);
    acc.x += cf * xv.x; acc.y += cf * xv.y; acc.z += cf * xv.z; acc.w += cf * xv.w;
  }
  *(float4*)(tpart + (size_t)chunk * NT + k4) = acc;
}

__global__ __launch_bounds__(256) void t_reduce_kernel(const float* __restrict__ tpart,
                                                       float* __restrict__ t) {
  int k = blockIdx.x * 256 + threadIdx.x;
  float s = 0.f;
#pragma unroll 8
  for (int ch = 0; ch < TCH; ch++) s += tpart[(size_t)ch * NT + k];
  t[k] = s;
}

// -------- r = X1 t - 0.5 Y1 x - U w - 0.5 eps x --------
__global__ __launch_bounds__(256) void r_kernel(const float* __restrict__ X,
                                                const float* __restrict__ Y1,
                                                const float* __restrict__ U,
                                                const float* __restrict__ t,
                                                const float* __restrict__ x,
                                                const float* __restrict__ w,
                                                float* __restrict__ r) {
  int row = blockIdx.x;
  float s1 = 0.f, s2 = 0.f, s3 = 0.f;
  const float* xr = X + (size_t)row * NT;
  for (int k = threadIdx.x * 4; k < NT; k += 1024) {
    float4 a = *(const float4*)(xr + k);
    float4 b = *(const float4*)(t + k);
    s1 += a.x * b.x + a.y * b.y + a.z * b.z + a.w * b.w;
  }
  const float* yr = Y1 + (size_t)row * NQ2;
  const float* ur = U + (size_t)row * NQ2;
  for (int k = threadIdx.x * 4; k < NQ2; k += 1024) {
    float4 a = *(const float4*)(yr + k);
    float4 b = *(const float4*)(x + k);
    s2 += a.x * b.x + a.y * b.y + a.z * b.z + a.w * b.w;
    float4 c2 = *(const float4*)(ur + k);
    float4 d2 = *(const float4*)(w + k);
    s3 += c2.x * d2.x + c2.y * d2.y + c2.z * d2.z + c2.w * d2.w;
  }
  float v = s1 - 0.5f * s2 - s3;
  float tot = block_reduce_256(v);
  if (threadIdx.x == 0) r[row] = tot - 0.5f * FEPS * x[row];
}

// ---------------- IR: res = r - (XP pz1 + eps z) ----------------
__global__ __launch_bounds__(256) void pz2_res_kernel(const float* __restrict__ XP,
                                                      const float* __restrict__ pz1,
                                                      const float* __restrict__ z,
                                                      const float* __restrict__ r,
                                                      float* __restrict__ res) {
  int row = blockIdx.x;
  float s = 0.f;
  const float* xr = XP + (size_t)row * NQ2;
  for (int k = threadIdx.x * 4; k < NQ2; k += 1024) {
    float4 a = *(const float4*)(xr + k);
    float4 b = *(const float4*)(pz1 + k);
    s += a.x * b.x + a.y * b.y + a.z * b.z + a.w * b.w;
  }
  float tot = block_reduce_256(s);
  if (threadIdx.x == 0) res[row] = r[row] - (tot + FEPS * z[row]);
}

__global__ __launch_bounds__(256) void axpy_kernel(float* __restrict__ z,
                                                   const float* __restrict__ dz) {
  int i = blockIdx.x * 256 + threadIdx.x;
  z[i] += dz[i];
}

// ---------------- out = z + B2 u ----------------
__global__ __launch_bounds__(256) void out_kernel(const float* __restrict__ z,
                                                  const float* __restrict__ B2,
                                                  const float* __restrict__ u,
                                                  float* __restrict__ out) {
  int i = blockIdx.x * 256 + threadIdx.x;
  float s = 0.f;
#pragma unroll
  for (int j = 0; j < NUU; j++) s += B2[(size_t)i * NUU + j] * u[j];
  out[i] = z[i] + s;
}

extern "C" void kernel_launch(void* const* d_in, const int* in_sizes, int n_in,
                              void* d_out, int out_size, void* d_ws, size_t ws_size,
                              hipStream_t stream) {
  (void)in_sizes; (void)n_in; (void)out_size; (void)ws_size;
  const float* x   = (const float*)d_in[1];
  const float* u   = (const float*)d_in[2];
  const float* X   = (const float*)d_in[3];
  const float* U   = (const float*)d_in[4];
  const float* Y1  = (const float*)d_in[5];
  const float* XP  = (const float*)d_in[6];
  const float* B2  = (const float*)d_in[7];
  const float* D12 = (const float*)d_in[8];
  float* out = (float*)d_out;

  float* ws     = (float*)d_ws;
  float* M      = ws;                           // 2048*2048
  float* vecs   = ws + (size_t)NQ2 * NQ2;
  float* invlam = vecs;
  float* c      = vecs + 2048;
  float* w      = vecs + 4096;
  float* r      = vecs + 6144;
  float* y      = vecs + 8192;
  float* z      = vecs + 10240;
  float* dz     = vecs + 12288;
  float* res    = vecs + 14336;
  float* t      = vecs + 16384;                 // 4096 (also pz1)
  float* tpart  = vecs + 20480;                 // 32*4096 (also gpart)
  float* gpart  = tpart;
  float* Xinv   = vecs + 20480 + 32 * 4096;     // 128*128

  int nsyrk = (NQ2 / 128) * (NQ2 / 128 + 1) / 2;  // 136
  dim3 gdim(NQ2 / 256, GCH);

  // lam, c = (U^T x)/lam + D12 u
  lam_kernel<<<NQ2, 256, 0, stream>>>(X, invlam);
  tgemv_part_kernel<<<gdim, 256, 0, stream>>>(U, x, gpart);
  finish_kernel<0><<<NQ2 / 256, 256, 0, stream>>>(gpart, invlam, D12, u, c);

  // H22 into M (MFMA bf16-split), then relu-triangular solve for w
  syrk_mfma_kernel<<<nsyrk, 256, 0, stream>>>(X + (size_t)NQ2 * NT, NT, NT, M, 0.0f);
  fwd_solve_kernel<0><<<1, 512, 0, stream>>>(M, c, invlam, w);

  // r
  dim3 tg(4, TCH);
  t_partial_kernel<<<tg, 256, 0, stream>>>(X, x, w, tpart);
  t_reduce_kernel<<<NT / 256, 256, 0, stream>>>(tpart, t);
  r_kernel<<<NQ2, 256, 0, stream>>>(X, Y1, U, t, x, w, r);
  tgemv_part_kernel<<<gdim, 256, 0, stream>>>(Y1, x, gpart);
  finish_kernel<1><<<NQ2 / 256, 256, 0, stream>>>(gpart, invlam, D12, u, r);

  // P = XP XP^T + eps I into M (MFMA), then blocked Cholesky (NSB=128)
  syrk_mfma_kernel<<<nsyrk, 256, 0, stream>>>(XP, NQ2, NQ2, M, FEPS);
  for (int k = 0; k < NSBLK; k++) {
    chol_diag128_kernel<<<1, 256, 0, stream>>>(M, Xinv, k);
    int rows_below = NQ2 - (k + 1) * NSB;
    if (rows_below > 0) {
      chol_panel128_kernel<<<rows_below / 128, 256, 0, stream>>>(M, Xinv, k);
      int m = NSBLK - 1 - k;
      chol_trail128_kernel<<<m * (m + 1) / 2, 256, 0, stream>>>(M, k);
    }
  }

  // solve P z = r
  fwd_solve_kernel<1><<<1, 512, 0, stream>>>(M, r, invlam, y);
  bwd_solve_kernel<<<1, 512, 0, stream>>>(M, y, z);

  // 2 steps of iterative refinement
  for (int it = 0; it < 2; it++) {
    tgemv_part_kernel<<<gdim, 256, 0, stream>>>(XP, z, gpart);
    finish_kernel<2><<<NQ2 / 256, 256, 0, stream>>>(gpart, invlam, D12, u, t);
    pz2_res_kernel<<<NQ2, 256, 0, stream>>>(XP, t, z, r, res);
    fwd_solve_kernel<1><<<1, 512, 0, stream>>>(M, res, invlam, y);
    bwd_solve_kernel<<<1, 512, 0, stream>>>(M, y, dz);
    axpy_kernel<<<NQ2 / 256, 256, 0, stream>>>(z, dz);
  }

  out_kernel<<<NQ2 / 256, 256, 0, stream>>>(z, B2, u, out);
}

// Round 8
// 4658.834 us; speedup vs baseline: 1.5655x; 1.5407x over previous
//
#include <hip/hip_runtime.h>
#include <math.h>

#define NQ2 2048      // nx = nq = 2048
#define NT  4096      // nx + nq
#define NUU 16
#define FEPS 0.01f
#define NB  64
#define NBLK 32       // 2048 / 64 (solve blocking)
#define NSB 128       // cholesky super-block
#define NSBLK 16      // 2048 / 128
#define GCH 16        // split-K chunks for transposed GEMVs

typedef __attribute__((ext_vector_type(8))) short short8;
typedef __attribute__((ext_vector_type(4))) float floatx4;

__device__ __forceinline__ float readlane_f(float v, int lane) {
  return __int_as_float(__builtin_amdgcn_readlane(__float_as_int(v), lane));
}

__device__ __forceinline__ unsigned short f2bf(float x) {
  unsigned u = __float_as_uint(x);
  unsigned r = u + 0x7FFFu + ((u >> 16) & 1u);
  return (unsigned short)(r >> 16);
}
__device__ __forceinline__ float bf2f(unsigned short h) {
  return __uint_as_float(((unsigned)h) << 16);
}

// ---------------- reductions ----------------
__device__ __forceinline__ float wave_reduce(float v) {
#pragma unroll
  for (int off = 32; off > 0; off >>= 1) v += __shfl_down(v, off, 64);
  return v;
}

__device__ __forceinline__ float block_reduce_256(float v) {
  __shared__ float sm[4];
  v = wave_reduce(v);
  if ((threadIdx.x & 63) == 0) sm[threadIdx.x >> 6] = v;
  __syncthreads();
  return (threadIdx.x == 0) ? (sm[0] + sm[1] + sm[2] + sm[3]) : 0.0f;
}

// ---------------- lam: inv(0.5*(||X2 row||^2 + eps)) ----------------
__global__ __launch_bounds__(256) void lam_kernel(const float* __restrict__ X,
                                                  float* __restrict__ invlam) {
  int row = blockIdx.x;
  const float* xr = X + (size_t)(NQ2 + row) * NT;
  float s = 0.f;
  for (int k = threadIdx.x * 4; k < NT; k += 1024) {
    float4 v = *(const float4*)(xr + k);
    s += v.x * v.x + v.y * v.y + v.z * v.z + v.w * v.w;
  }
  float tot = block_reduce_256(s);
  if (threadIdx.x == 0) invlam[row] = 1.0f / (0.5f * (tot + FEPS));
}

// ---------------- split-K transposed GEMV ----------------
__global__ __launch_bounds__(256) void tgemv_part_kernel(const float* __restrict__ A,
                                                         const float* __restrict__ v,
                                                         float* __restrict__ part) {
  int col = blockIdx.x * 256 + threadIdx.x;
  int ch = blockIdx.y;
  int i0 = ch * (NQ2 / GCH), i1 = i0 + NQ2 / GCH;
  float s = 0.f;
#pragma unroll 4
  for (int i = i0; i < i1; i++) s = fmaf(A[(size_t)i * NQ2 + col], v[i], s);
  part[(size_t)ch * NQ2 + col] = s;
}

// FM 0: c = sum*invlam + D12 u   FM 1: r += 0.5*sum   FM 2: dst = sum
template <int FM>
__global__ __launch_bounds__(256) void finish_kernel(const float* __restrict__ part,
                                                     const float* __restrict__ invlam,
                                                     const float* __restrict__ D12,
                                                     const float* __restrict__ u,
                                                     float* __restrict__ dst) {
  int col = blockIdx.x * 256 + threadIdx.x;
  float s = 0.f;
#pragma unroll
  for (int ch = 0; ch < GCH; ch++) s += part[(size_t)ch * NQ2 + col];
  if (FM == 0) {
    float d = 0.f;
#pragma unroll
    for (int j = 0; j < NUU; j++) d += D12[(size_t)col * NUU + j] * u[j];
    dst[col] = s * invlam[col] + d;
  } else if (FM == 1) {
    dst[col] += 0.5f * s;
  } else {
    dst[col] = s;
  }
}

// ============ MFMA SYRK (bf16 hi/lo split): C = A A^T (+eps diag), lower 128-tiles ====
__global__ __launch_bounds__(256) void syrk_mfma_kernel(const float* __restrict__ A,
                                                        int lda, int K,
                                                        float* __restrict__ C, float eps) {
  int L = blockIdx.x;
  int bi = (int)((sqrtf(8.0f * (float)L + 1.0f) - 1.0f) * 0.5f);
  while ((bi + 1) * (bi + 2) / 2 <= L) bi++;
  while (bi * (bi + 1) / 2 > L) bi--;
  int bj = L - bi * (bi + 1) / 2;
  int row0 = bi * 128, col0 = bj * 128;

  __shared__ __align__(16) short Ah[4096], Al[4096], Bh[4096], Bl[4096];

  int tid = threadIdx.x;
  int l = tid & 63;
  int w = tid >> 6;
  int wr = w >> 1, wc = w & 1;

  int g0 = tid, g1 = tid + 256;
  int ar0 = (g0 >> 6) * 16 + (g0 & 15), ak0 = ((g0 >> 4) & 3) * 8;
  int ar1 = (g1 >> 6) * 16 + (g1 & 15), ak1 = ((g1 >> 4) & 3) * 8;

  const float* pa0 = A + (size_t)(row0 + ar0) * lda + ak0;
  const float* pa1 = A + (size_t)(row0 + ar1) * lda + ak1;
  const float* pb0 = A + (size_t)(col0 + ar0) * lda + ak0;
  const float* pb1 = A + (size_t)(col0 + ar1) * lda + ak1;

  floatx4 acc[4][4];
#pragma unroll
  for (int m = 0; m < 4; m++)
#pragma unroll
    for (int n = 0; n < 4; n++) acc[m][n] = (floatx4){0.f, 0.f, 0.f, 0.f};

  float xa0[8], xa1[8], xb0[8], xb1[8];
  {
    float4 t0 = *(const float4*)(pa0), t1 = *(const float4*)(pa0 + 4);
    xa0[0]=t0.x; xa0[1]=t0.y; xa0[2]=t0.z; xa0[3]=t0.w; xa0[4]=t1.x; xa0[5]=t1.y; xa0[6]=t1.z; xa0[7]=t1.w;
    t0 = *(const float4*)(pa1); t1 = *(const float4*)(pa1 + 4);
    xa1[0]=t0.x; xa1[1]=t0.y; xa1[2]=t0.z; xa1[3]=t0.w; xa1[4]=t1.x; xa1[5]=t1.y; xa1[6]=t1.z; xa1[7]=t1.w;
    t0 = *(const float4*)(pb0); t1 = *(const float4*)(pb0 + 4);
    xb0[0]=t0.x; xb0[1]=t0.y; xb0[2]=t0.z; xb0[3]=t0.w; xb0[4]=t1.x; xb0[5]=t1.y; xb0[6]=t1.z; xb0[7]=t1.w;
    t0 = *(const float4*)(pb1); t1 = *(const float4*)(pb1 + 4);
    xb1[0]=t0.x; xb1[1]=t0.y; xb1[2]=t0.z; xb1[3]=t0.w; xb1[4]=t1.x; xb1[5]=t1.y; xb1[6]=t1.z; xb1[7]=t1.w;
  }

  for (int k0 = 0; k0 < K; k0 += 32) {
    __syncthreads();
    {
      short8 h, lo;
#pragma unroll
      for (int j = 0; j < 8; j++) { unsigned short hb = f2bf(xa0[j]); h[j] = (short)hb; lo[j] = (short)f2bf(xa0[j] - bf2f(hb)); }
      *(short8*)&Ah[g0 * 8] = h; *(short8*)&Al[g0 * 8] = lo;
#pragma unroll
      for (int j = 0; j < 8; j++) { unsigned short hb = f2bf(xa1[j]); h[j] = (short)hb; lo[j] = (short)f2bf(xa1[j] - bf2f(hb)); }
      *(short8*)&Ah[g1 * 8] = h; *(short8*)&Al[g1 * 8] = lo;
#pragma unroll
      for (int j = 0; j < 8; j++) { unsigned short hb = f2bf(xb0[j]); h[j] = (short)hb; lo[j] = (short)f2bf(xb0[j] - bf2f(hb)); }
      *(short8*)&Bh[g0 * 8] = h; *(short8*)&Bl[g0 * 8] = lo;
#pragma unroll
      for (int j = 0; j < 8; j++) { unsigned short hb = f2bf(xb1[j]); h[j] = (short)hb; lo[j] = (short)f2bf(xb1[j] - bf2f(hb)); }
      *(short8*)&Bh[g1 * 8] = h; *(short8*)&Bl[g1 * 8] = lo;
    }
    __syncthreads();
    if (k0 + 32 < K) {
      const float* q = pa0 + k0 + 32;
      float4 t0 = *(const float4*)(q), t1 = *(const float4*)(q + 4);
      xa0[0]=t0.x; xa0[1]=t0.y; xa0[2]=t0.z; xa0[3]=t0.w; xa0[4]=t1.x; xa0[5]=t1.y; xa0[6]=t1.z; xa0[7]=t1.w;
      q = pa1 + k0 + 32; t0 = *(const float4*)(q); t1 = *(const float4*)(q + 4);
      xa1[0]=t0.x; xa1[1]=t0.y; xa1[2]=t0.z; xa1[3]=t0.w; xa1[4]=t1.x; xa1[5]=t1.y; xa1[6]=t1.z; xa1[7]=t1.w;
      q = pb0 + k0 + 32; t0 = *(const float4*)(q); t1 = *(const float4*)(q + 4);
      xb0[0]=t0.x; xb0[1]=t0.y; xb0[2]=t0.z; xb0[3]=t0.w; xb0[4]=t1.x; xb0[5]=t1.y; xb0[6]=t1.z; xb0[7]=t1.w;
      q = pb1 + k0 + 32; t0 = *(const float4*)(q); t1 = *(const float4*)(q + 4);
      xb1[0]=t0.x; xb1[1]=t0.y; xb1[2]=t0.z; xb1[3]=t0.w; xb1[4]=t1.x; xb1[5]=t1.y; xb1[6]=t1.z; xb1[7]=t1.w;
    }
    short8 amh[4], aml[4], bnh[4], bnl[4];
#pragma unroll
    for (int m = 0; m < 4; m++) {
      int ga = ((wr * 4 + m) * 64 + l) * 8;
      amh[m] = *(const short8*)&Ah[ga];
      aml[m] = *(const short8*)&Al[ga];
    }
#pragma unroll
    for (int n = 0; n < 4; n++) {
      int gb = ((wc * 4 + n) * 64 + l) * 8;
      bnh[n] = *(const short8*)&Bh[gb];
      bnl[n] = *(const short8*)&Bl[gb];
    }
#pragma unroll
    for (int m = 0; m < 4; m++)
#pragma unroll
      for (int n = 0; n < 4; n++) {
        acc[m][n] = __builtin_amdgcn_mfma_f32_16x16x32_bf16(amh[m], bnh[n], acc[m][n], 0, 0, 0);
        acc[m][n] = __builtin_amdgcn_mfma_f32_16x16x32_bf16(amh[m], bnl[n], acc[m][n], 0, 0, 0);
        acc[m][n] = __builtin_amdgcn_mfma_f32_16x16x32_bf16(aml[m], bnh[n], acc[m][n], 0, 0, 0);
      }
  }

  int lr = (l >> 4) * 4;
  int lc = l & 15;
#pragma unroll
  for (int m = 0; m < 4; m++)
#pragma unroll
    for (int n = 0; n < 4; n++)
#pragma unroll
      for (int r = 0; r < 4; r++) {
        int gi = row0 + wr * 64 + m * 16 + lr + r;
        int gj = col0 + wc * 64 + n * 16 + lc;
        float v = acc[m][n][r];
        if (gi == gj) v += eps;
        C[(size_t)gi * NQ2 + gj] = v;
      }
}

// ======== register-chain 64x64 Cholesky factor (one wave; lane = row) ========
__device__ __attribute__((noinline)) void factor64(float (*Ls)[NSB + 1], int o, int lane) {
  float a[64];
#pragma unroll
  for (int j = 0; j < 64; j++) a[j] = Ls[o + lane][o + j];
#pragma unroll
  for (int j = 0; j < 64; j++) {
    float d = readlane_f(a[j], j);
    float rs = rsqrtf(fmaxf(d, 1e-20f));
    a[j] *= rs;
#pragma unroll
    for (int k2 = j + 1; k2 < 64; k2++) {
      float ljk = readlane_f(a[j], k2);
      a[k2] = fmaf(-a[j], ljk, a[k2]);
    }
  }
#pragma unroll
  for (int j = 0; j < 64; j++) Ls[o + lane][o + j] = a[j];
}

// ======== Cholesky diag: register-based factor + TRSM + SYRK + inverse ========
__global__ __launch_bounds__(256) void chol_diag128_kernel(float* __restrict__ M_,
                                                           float* __restrict__ Xinv, int k) {
  __shared__ float Ls[NSB][NSB + 1];
  __shared__ float Xs[NSB][NSB + 1];
  int b0 = k * NSB;
  int tid = threadIdx.x;
  int wv = tid >> 6;
  int lane = tid & 63;
  for (int e = tid; e < NSB * NSB; e += 256) {
    int rr = e >> 7, cc = e & 127;
    Ls[rr][cc] = M_[(size_t)(b0 + rr) * NQ2 + b0 + cc];
  }
  __syncthreads();
  // phase 1: factor D1 (wave 0, registers + readlane)
  if (wv == 0) factor64(Ls, 0, lane);
  __syncthreads();
  // phase 2: TRSM rows 64..127 vs L11 (wave 0, lane = row, L11 broadcast reads)
  if (wv == 0) {
    float v[64];
#pragma unroll
    for (int j = 0; j < 64; j++) v[j] = Ls[64 + lane][j];
#pragma unroll
    for (int t = 0; t < 64; t++) {
      float dinv = 1.0f / Ls[t][t];
      v[t] *= dinv;
#pragma unroll
      for (int j = t + 1; j < 64; j++) v[j] = fmaf(-v[t], Ls[j][t], v[j]);
    }
#pragma unroll
    for (int j = 0; j < 64; j++) Ls[64 + lane][j] = v[j];
  }
  __syncthreads();
  // phase 3: SYRK D2 -= L21 L21^T (all waves, full 64x64)
  for (int e = tid; e < 64 * 64; e += 256) {
    int rr = e >> 6, cc = e & 63;
    float s0 = 0.f, s1 = 0.f;
#pragma unroll 8
    for (int t = 0; t < 64; t += 2) {
      s0 = fmaf(Ls[64 + rr][t], Ls[64 + cc][t], s0);
      s1 = fmaf(Ls[64 + rr][t + 1], Ls[64 + cc][t + 1], s1);
    }
    Ls[64 + rr][64 + cc] -= (s0 + s1);
  }
  __syncthreads();
  // phase 4: factor D2 (wave 0)
  if (wv == 0) factor64(Ls, 64, lane);
  __syncthreads();
  // phase 5: inverses (wave 0 -> X11, wave 1 -> X22); lane = column, registers
  if (wv < 2) {
    int o = wv * 64;
    int c = lane;
    float x[64];
#pragma unroll
    for (int i = 0; i < 64; i++) x[i] = 0.f;
#pragma unroll
    for (int t = 0; t < 64; t++) {
      float rcpd = 1.0f / Ls[o + t][o + t];
      x[t] = (t == c) ? rcpd : x[t] * rcpd;
#pragma unroll
      for (int i = t + 1; i < 64; i++) x[i] = fmaf(-Ls[o + i][o + t], x[t], x[i]);
    }
#pragma unroll
    for (int i = 0; i < 64; i++) Xs[o + i][o + c] = x[i];
  }
  __syncthreads();
  // phase 6: T = L21 * X11 -> Xs[0:64][64:128]
  for (int e = tid; e < 64 * 64; e += 256) {
    int rr = e >> 6, cc = e & 63;
    float s0 = 0.f, s1 = 0.f;
#pragma unroll 8
    for (int t = 0; t < 64; t += 2) {
      s0 = fmaf(Ls[64 + rr][t], Xs[t][cc], s0);
      s1 = fmaf(Ls[64 + rr][t + 1], Xs[t + 1][cc], s1);
    }
    Xs[rr][64 + cc] = s0 + s1;
  }
  __syncthreads();
  // phase 7: X21 = -X22 * T -> Xs[64:128][0:64]
  for (int e = tid; e < 64 * 64; e += 256) {
    int rr = e >> 6, cc = e & 63;
    float s0 = 0.f, s1 = 0.f;
#pragma unroll 8
    for (int t = 0; t < 64; t += 2) {
      s0 = fmaf(Xs[64 + rr][64 + t], Xs[t][64 + cc], s0);
      s1 = fmaf(Xs[64 + rr][64 + t + 1], Xs[t + 1][64 + cc], s1);
    }
    Xs[64 + rr][cc] = -(s0 + s1);
  }
  __syncthreads();
  // phase 8: zero temp quadrant (upper-right of Xinv)
  for (int e = tid; e < 64 * 64; e += 256) {
    int rr = e >> 6, cc = e & 63;
    Xs[rr][64 + cc] = 0.f;
  }
  __syncthreads();
  // write back L (lower) and Xinv (full)
  for (int e = tid; e < NSB * NSB; e += 256) {
    int rr = e >> 7, cc = e & 127;
    if (cc <= rr) M_[(size_t)(b0 + rr) * NQ2 + b0 + cc] = Ls[rr][cc];
    Xinv[e] = Xs[rr][cc];
  }
}

// ======== Cholesky panel as GEMM: L21 = A21 * Xinv^T  (in place) ========
__global__ __launch_bounds__(256) void chol_panel128_kernel(float* __restrict__ M_,
                                                            const float* __restrict__ Xinv,
                                                            int k) {
  int kc = k * NSB;
  int rb0 = kc + NSB + blockIdx.x * 128;
  __shared__ float As[16][128];
  __shared__ float Bs[16][128];
  int tid = threadIdx.x;
  int tx = tid & 15, ty = tid >> 4;
  int sr = tid >> 1, ks = (tid & 1) * 8;

  const float* ap = M_ + (size_t)(rb0 + sr) * NQ2 + kc + ks;
  const float* bp = Xinv + sr * 128 + ks;
  float4 a0 = *(const float4*)(ap), a1 = *(const float4*)(ap + 4);
  float4 b0 = *(const float4*)(bp), b1 = *(const float4*)(bp + 4);

  float acc[8][8] = {{0.f}};
  for (int k0 = 0; k0 < 128; k0 += 16) {
    __syncthreads();
    As[ks + 0][sr] = a0.x; As[ks + 1][sr] = a0.y; As[ks + 2][sr] = a0.z; As[ks + 3][sr] = a0.w;
    As[ks + 4][sr] = a1.x; As[ks + 5][sr] = a1.y; As[ks + 6][sr] = a1.z; As[ks + 7][sr] = a1.w;
    Bs[ks + 0][sr] = b0.x; Bs[ks + 1][sr] = b0.y; Bs[ks + 2][sr] = b0.z; Bs[ks + 3][sr] = b0.w;
    Bs[ks + 4][sr] = b1.x; Bs[ks + 5][sr] = b1.y; Bs[ks + 6][sr] = b1.z; Bs[ks + 7][sr] = b1.w;
    __syncthreads();
    if (k0 + 16 < 128) {
      const float* q = ap + k0 + 16;
      a0 = *(const float4*)(q); a1 = *(const float4*)(q + 4);
      q = bp + k0 + 16;
      b0 = *(const float4*)(q); b1 = *(const float4*)(q + 4);
    }
#pragma unroll
    for (int kk = 0; kk < 16; kk++) {
      float4 aL = *(const float4*)&As[kk][ty * 4];
      float4 aH = *(const float4*)&As[kk][64 + ty * 4];
      float4 bL = *(const float4*)&Bs[kk][tx * 4];
      float4 bH = *(const float4*)&Bs[kk][64 + tx * 4];
      float aa[8] = {aL.x, aL.y, aL.z, aL.w, aH.x, aH.y, aH.z, aH.w};
      float bb[8] = {bL.x, bL.y, bL.z, bL.w, bH.x, bH.y, bH.z, bH.w};
#pragma unroll
      for (int i = 0; i < 8; i++)
#pragma unroll
        for (int j = 0; j < 8; j++) acc[i][j] = fmaf(aa[i], bb[j], acc[i][j]);
    }
  }
#pragma unroll
  for (int ii = 0; ii < 8; ii++) {
    int gi = rb0 + ((ii >> 2) * 64) + ty * 4 + (ii & 3);
#pragma unroll
    for (int half = 0; half < 2; half++) {
      int gj0 = kc + half * 64 + tx * 4;
      float4 o;
      o.x = acc[ii][half * 4 + 0]; o.y = acc[ii][half * 4 + 1];
      o.z = acc[ii][half * 4 + 2]; o.w = acc[ii][half * 4 + 3];
      *(float4*)&M_[(size_t)gi * NQ2 + gj0] = o;
    }
  }
}

// ======== Cholesky trailing: C -= L21 L21^T, 128-tiles, K=128 ========
__global__ __launch_bounds__(256) void chol_trail128_kernel(float* __restrict__ M_, int k) {
  int L = blockIdx.x;
  int bi = (int)((sqrtf(8.0f * (float)L + 1.0f) - 1.0f) * 0.5f);
  while ((bi + 1) * (bi + 2) / 2 <= L) bi++;
  while (bi * (bi + 1) / 2 > L) bi--;
  int bj = L - bi * (bi + 1) / 2;
  int row0 = (k + 1 + bi) * NSB, col0 = (k + 1 + bj) * NSB, kc = k * NSB;

  __shared__ float As[16][128];
  __shared__ float Bs[16][128];
  int tid = threadIdx.x;
  int tx = tid & 15, ty = tid >> 4;
  int sr = tid >> 1, ks = (tid & 1) * 8;

  const float* ap = M_ + (size_t)(row0 + sr) * NQ2 + kc + ks;
  const float* bp = M_ + (size_t)(col0 + sr) * NQ2 + kc + ks;
  float4 a0 = *(const float4*)(ap), a1 = *(const float4*)(ap + 4);
  float4 b0 = *(const float4*)(bp), b1 = *(const float4*)(bp + 4);

  float acc[8][8] = {{0.f}};
  for (int k0 = 0; k0 < 128; k0 += 16) {
    __syncthreads();
    As[ks + 0][sr] = a0.x; As[ks + 1][sr] = a0.y; As[ks + 2][sr] = a0.z; As[ks + 3][sr] = a0.w;
    As[ks + 4][sr] = a1.x; As[ks + 5][sr] = a1.y; As[ks + 6][sr] = a1.z; As[ks + 7][sr] = a1.w;
    Bs[ks + 0][sr] = b0.x; Bs[ks + 1][sr] = b0.y; Bs[ks + 2][sr] = b0.z; Bs[ks + 3][sr] = b0.w;
    Bs[ks + 4][sr] = b1.x; Bs[ks + 5][sr] = b1.y; Bs[ks + 6][sr] = b1.z; Bs[ks + 7][sr] = b1.w;
    __syncthreads();
    if (k0 + 16 < 128) {
      const float* q = ap + k0 + 16;
      a0 = *(const float4*)(q); a1 = *(const float4*)(q + 4);
      q = bp + k0 + 16;
      b0 = *(const float4*)(q); b1 = *(const float4*)(q + 4);
    }
#pragma unroll
    for (int kk = 0; kk < 16; kk++) {
      float4 aL = *(const float4*)&As[kk][ty * 4];
      float4 aH = *(const float4*)&As[kk][64 + ty * 4];
      float4 bL = *(const float4*)&Bs[kk][tx * 4];
      float4 bH = *(const float4*)&Bs[kk][64 + tx * 4];
      float aa[8] = {aL.x, aL.y, aL.z, aL.w, aH.x, aH.y, aH.z, aH.w};
      float bb[8] = {bL.x, bL.y, bL.z, bL.w, bH.x, bH.y, bH.z, bH.w};
#pragma unroll
      for (int i = 0; i < 8; i++)
#pragma unroll
        for (int j = 0; j < 8; j++) acc[i][j] = fmaf(aa[i], bb[j], acc[i][j]);
    }
  }
#pragma unroll
  for (int ii = 0; ii < 8; ii++) {
    int gi = row0 + ((ii >> 2) * 64) + ty * 4 + (ii & 3);
#pragma unroll
    for (int half = 0; half < 2; half++) {
      int gj0 = col0 + half * 64 + tx * 4;
      float* cp = &M_[(size_t)gi * NQ2 + gj0];
      float4 v = *(const float4*)cp;
      v.x -= acc[ii][half * 4 + 0]; v.y -= acc[ii][half * 4 + 1];
      v.z -= acc[ii][half * 4 + 2]; v.w -= acc[ii][half * 4 + 3];
      *(float4*)cp = v;
    }
  }
}

// -------- blocked forward substitution: 512 thr, 2 barriers/block, tile prefetch --------
// MODE 0: w_i = relu(c_i - (sum_{j<i} M[i,j] w_j) * invlam_i)
// MODE 1: y_i = (r_i - sum_{j<i} L[i,j] y_j) / L[i,i]
template <int MODE>
__global__ __launch_bounds__(512) void fwd_solve_kernel(const float* __restrict__ M_,
                                                        const float* __restrict__ rhs,
                                                        const float* __restrict__ invlam,
                                                        float* __restrict__ out) {
  __shared__ float partial[NQ2];
  __shared__ float il[NQ2];
  __shared__ float tile[2][NB][NB + 1];
  __shared__ float vblk[NB];
  int tid = threadIdx.x;
  int rquad = tid >> 2;   // 0..127
  int l4 = tid & 3;
  for (int i = tid; i < NQ2; i += 512) {
    partial[i] = rhs[i];
    if (MODE == 0) il[i] = invlam[i];
  }
  for (int e = tid; e < NB * NB; e += 512) {
    int rr = e >> 6, cc = e & 63;
    tile[0][rr][cc] = M_[(size_t)rr * NQ2 + cc];
  }
  __syncthreads();
  for (int b = 0; b < NBLK; b++) {
    int cur = b & 1;
    int b0 = b * NB;
    if (tid < 64) {
      // serial chain (wave 0)
      int l = tid;
      float creg = partial[b0 + l];
      float ilreg = (MODE == 0) ? il[b0 + l] : 0.f;
      float dinv = (MODE == 1) ? (1.0f / tile[cur][l][l]) : 0.f;
      float acc = 0.f;
      float wfin = 0.f;
#pragma unroll
      for (int i = 0; i < NB; i++) {
        float cand;
        if (MODE == 0) cand = fmaxf(creg - acc * ilreg, 0.f);
        else           cand = (creg - acc) * dinv;
        float wi = readlane_f(cand, i);
        acc = fmaf(tile[cur][l][i], wi, acc);
        if (l == i) wfin = wi;
      }
      vblk[l] = wfin;
      out[b0 + l] = wfin;
    } else if (b + 1 < NBLK) {
      // waves 1..7 prefetch next diag tile
      int b1 = b0 + NB;
      for (int e = tid - 64; e < NB * NB; e += 448) {
        int rr = e >> 6, cc = e & 63;
        tile[cur ^ 1][rr][cc] = M_[(size_t)(b1 + rr) * NQ2 + b1 + cc];
      }
    }
    __syncthreads();
    // GEMV: 4 lanes/row, 2-row unroll => 256 rows/iter
    float4 v0 = *(const float4*)(&vblk[l4 * 16]);
    float4 v1 = *(const float4*)(&vblk[l4 * 16 + 4]);
    float4 v2 = *(const float4*)(&vblk[l4 * 16 + 8]);
    float4 v3 = *(const float4*)(&vblk[l4 * 16 + 12]);
    for (int base = b0 + NB; base < NQ2; base += 256) {
      int row0 = base + rquad;
      int row1 = row0 + 128;
      float acc0 = 0.f, acc1 = 0.f;
      if (row0 < NQ2) {
        const float* mr = M_ + (size_t)row0 * NQ2 + b0 + l4 * 16;
        float4 m0 = *(const float4*)(mr);
        float4 m1 = *(const float4*)(mr + 4);
        float4 m2 = *(const float4*)(mr + 8);
        float4 m3 = *(const float4*)(mr + 12);
        acc0 = m0.x * v0.x + m0.y * v0.y + m0.z * v0.z + m0.w * v0.w
             + m1.x * v1.x + m1.y * v1.y + m1.z * v1.z + m1.w * v1.w
             + m2.x * v2.x + m2.y * v2.y + m2.z * v2.z + m2.w * v2.w
             + m3.x * v3.x + m3.y * v3.y + m3.z * v3.z + m3.w * v3.w;
      }
      if (row1 < NQ2) {
        const float* mr = M_ + (size_t)row1 * NQ2 + b0 + l4 * 16;
        float4 m0 = *(const float4*)(mr);
        float4 m1 = *(const float4*)(mr + 4);
        float4 m2 = *(const float4*)(mr + 8);
        float4 m3 = *(const float4*)(mr + 12);
        acc1 = m0.x * v0.x + m0.y * v0.y + m0.z * v0.z + m0.w * v0.w
             + m1.x * v1.x + m1.y * v1.y + m1.z * v1.z + m1.w * v1.w
             + m2.x * v2.x + m2.y * v2.y + m2.z * v2.z + m2.w * v2.w
             + m3.x * v3.x + m3.y * v3.y + m3.z * v3.z + m3.w * v3.w;
      }
      acc0 += __shfl_xor(acc0, 1);
      acc0 += __shfl_xor(acc0, 2);
      acc1 += __shfl_xor(acc1, 1);
      acc1 += __shfl_xor(acc1, 2);
      if (l4 == 0) {
        if (row0 < NQ2) {
          if (MODE == 0) partial[row0] -= acc0 * il[row0];
          else           partial[row0] -= acc0;
        }
        if (row1 < NQ2) {
          if (MODE == 0) partial[row1] -= acc1 * il[row1];
          else           partial[row1] -= acc1;
        }
      }
    }
    __syncthreads();
  }
}

// -------- blocked backward substitution: L^T z = y (512 thr, prefetch) --------
__global__ __launch_bounds__(512) void bwd_solve_kernel(const float* __restrict__ M_,
                                                        const float* __restrict__ rhs,
                                                        float* __restrict__ out) {
  __shared__ float partial[NQ2];
  __shared__ float tile[2][NB][NB + 1];  // tile[.][a][b] = L[b0+b][b0+a]
  __shared__ float vblk[NB];
  int tid = threadIdx.x;
  for (int i = tid; i < NQ2; i += 512) partial[i] = rhs[i];
  {
    int b0 = (NBLK - 1) * NB;
    for (int e = tid; e < NB * NB; e += 512) {
      int rr = e >> 6, cc = e & 63;
      tile[(NBLK - 1) & 1][cc][rr] = M_[(size_t)(b0 + rr) * NQ2 + b0 + cc];
    }
  }
  __syncthreads();
  for (int b = NBLK - 1; b >= 0; b--) {
    int cur = b & 1;
    int b0 = b * NB;
    if (tid < 64) {
      int l = tid;
      float creg = partial[b0 + l];
      float dinv = 1.0f / tile[cur][l][l];
      float acc = 0.f;
      float zfin = 0.f;
#pragma unroll
      for (int i = NB - 1; i >= 0; i--) {
        float cand = (creg - acc) * dinv;
        float zi = readlane_f(cand, i);
        acc = fmaf(tile[cur][l][i], zi, acc);
        if (l == i) zfin = zi;
      }
      vblk[l] = zfin;
      out[b0 + l] = zfin;
    } else if (b > 0) {
      int b1 = b0 - NB;
      for (int e = tid - 64; e < NB * NB; e += 448) {
        int rr = e >> 6, cc = e & 63;
        tile[cur ^ 1][cc][rr] = M_[(size_t)(b1 + rr) * NQ2 + b1 + cc];
      }
    }
    __syncthreads();
    for (int i = tid; i < b0; i += 512) {
      float acc = 0.f;
#pragma unroll 16
      for (int l = 0; l < NB; l++) acc += M_[(size_t)(b0 + l) * NQ2 + i] * vblk[l];
      partial[i] -= acc;
    }
    __syncthreads();
  }
}

// ---------------- t = -0.5 X1^T x - X2^T w ----------------
#define TCH 32
__global__ __launch_bounds__(256) void t_partial_kernel(const float* __restrict__ X,
                                                        const float* __restrict__ x,
                                                        const float* __restrict__ w,
                                                        float* __restrict__ tpart) {
  int k4 = (blockIdx.x * 256 + threadIdx.x) * 4;
  int chunk = blockIdx.y;
  int i0 = chunk * (NT / TCH);
  float4 acc = {0.f, 0.f, 0.f, 0.f};
  for (int i = i0; i < i0 + NT / TCH; i++) {
    float cf = (i < NQ2) ? (-0.5f * x[i]) : (-w[i - NQ2]);
    float4 xv = *(const float4*)(X + (size_t)i * NT + k4);
    acc.x += cf * xv.x; acc.y += cf * xv.y; acc.z += cf * xv.z; acc.w += cf * xv.w;
  }
  *(float4*)(tpart + (size_t)chunk * NT + k4) = acc;
}

__global__ __launch_bounds__(256) void t_reduce_kernel(const float* __restrict__ tpart,
                                                       float* __restrict__ t) {
  int k = blockIdx.x * 256 + threadIdx.x;
  float s = 0.f;
#pragma unroll 8
  for (int ch = 0; ch < TCH; ch++) s += tpart[(size_t)ch * NT + k];
  t[k] = s;
}

// -------- r = X1 t - 0.5 Y1 x - U w - 0.5 eps x --------
__global__ __launch_bounds__(256) void r_kernel(const float* __restrict__ X,
                                                const float* __restrict__ Y1,
                                                const float* __restrict__ U,
                                                const float* __restrict__ t,
                                                const float* __restrict__ x,
                                                const float* __restrict__ w,
                                                float* __restrict__ r) {
  int row = blockIdx.x;
  float s1 = 0.f, s2 = 0.f, s3 = 0.f;
  const float* xr = X + (size_t)row * NT;
  for (int k = threadIdx.x * 4; k < NT; k += 1024) {
    float4 a = *(const float4*)(xr + k);
    float4 b = *(const float4*)(t + k);
    s1 += a.x * b.x + a.y * b.y + a.z * b.z + a.w * b.w;
  }
  const float* yr = Y1 + (size_t)row * NQ2;
  const float* ur = U + (size_t)row * NQ2;
  for (int k = threadIdx.x * 4; k < NQ2; k += 1024) {
    float4 a = *(const float4*)(yr + k);
    float4 b = *(const float4*)(x + k);
    s2 += a.x * b.x + a.y * b.y + a.z * b.z + a.w * b.w;
    float4 c2 = *(const float4*)(ur + k);
    float4 d2 = *(const float4*)(w + k);
    s3 += c2.x * d2.x + c2.y * d2.y + c2.z * d2.z + c2.w * d2.w;
  }
  float v = s1 - 0.5f * s2 - s3;
  float tot = block_reduce_256(v);
  if (threadIdx.x == 0) r[row] = tot - 0.5f * FEPS * x[row];
}

// ---------------- IR: res = r - (XP pz1 + eps z) ----------------
__global__ __launch_bounds__(256) void pz2_res_kernel(const float* __restrict__ XP,
                                                      const float* __restrict__ pz1,
                                                      const float* __restrict__ z,
                                                      const float* __restrict__ r,
                                                      float* __restrict__ res) {
  int row = blockIdx.x;
  float s = 0.f;
  const float* xr = XP + (size_t)row * NQ2;
  for (int k = threadIdx.x * 4; k < NQ2; k += 1024) {
    float4 a = *(const float4*)(xr + k);
    float4 b = *(const float4*)(pz1 + k);
    s += a.x * b.x + a.y * b.y + a.z * b.z + a.w * b.w;
  }
  float tot = block_reduce_256(s);
  if (threadIdx.x == 0) res[row] = r[row] - (tot + FEPS * z[row]);
}

__global__ __launch_bounds__(256) void axpy_kernel(float* __restrict__ z,
                                                   const float* __restrict__ dz) {
  int i = blockIdx.x * 256 + threadIdx.x;
  z[i] += dz[i];
}

// ---------------- out = z + B2 u ----------------
__global__ __launch_bounds__(256) void out_kernel(const float* __restrict__ z,
                                                  const float* __restrict__ B2,
                                                  const float* __restrict__ u,
                                                  float* __restrict__ out) {
  int i = blockIdx.x * 256 + threadIdx.x;
  float s = 0.f;
#pragma unroll
  for (int j = 0; j < NUU; j++) s += B2[(size_t)i * NUU + j] * u[j];
  out[i] = z[i] + s;
}

extern "C" void kernel_launch(void* const* d_in, const int* in_sizes, int n_in,
                              void* d_out, int out_size, void* d_ws, size_t ws_size,
                              hipStream_t stream) {
  (void)in_sizes; (void)n_in; (void)out_size; (void)ws_size;
  const float* x   = (const float*)d_in[1];
  const float* u   = (const float*)d_in[2];
  const float* X   = (const float*)d_in[3];
  const float* U   = (const float*)d_in[4];
  const float* Y1  = (const float*)d_in[5];
  const float* XP  = (const float*)d_in[6];
  const float* B2  = (const float*)d_in[7];
  const float* D12 = (const float*)d_in[8];
  float* out = (float*)d_out;

  float* ws     = (float*)d_ws;
  float* M      = ws;                           // 2048*2048
  float* vecs   = ws + (size_t)NQ2 * NQ2;
  float* invlam = vecs;
  float* c      = vecs + 2048;
  float* w      = vecs + 4096;
  float* r      = vecs + 6144;
  float* y      = vecs + 8192;
  float* z      = vecs + 10240;
  float* dz     = vecs + 12288;
  float* res    = vecs + 14336;
  float* t      = vecs + 16384;                 // 4096 (also pz1)
  float* tpart  = vecs + 20480;                 // 32*4096 (also gpart)
  float* gpart  = tpart;
  float* Xinv   = vecs + 20480 + 32 * 4096;     // 128*128

  int nsyrk = (NQ2 / 128) * (NQ2 / 128 + 1) / 2;  // 136
  dim3 gdim(NQ2 / 256, GCH);

  // lam, c = (U^T x)/lam + D12 u
  lam_kernel<<<NQ2, 256, 0, stream>>>(X, invlam);
  tgemv_part_kernel<<<gdim, 256, 0, stream>>>(U, x, gpart);
  finish_kernel<0><<<NQ2 / 256, 256, 0, stream>>>(gpart, invlam, D12, u, c);

  // H22 into M (MFMA bf16-split), then relu-triangular solve for w
  syrk_mfma_kernel<<<nsyrk, 256, 0, stream>>>(X + (size_t)NQ2 * NT, NT, NT, M, 0.0f);
  fwd_solve_kernel<0><<<1, 512, 0, stream>>>(M, c, invlam, w);

  // r
  dim3 tg(4, TCH);
  t_partial_kernel<<<tg, 256, 0, stream>>>(X, x, w, tpart);
  t_reduce_kernel<<<NT / 256, 256, 0, stream>>>(tpart, t);
  r_kernel<<<NQ2, 256, 0, stream>>>(X, Y1, U, t, x, w, r);
  tgemv_part_kernel<<<gdim, 256, 0, stream>>>(Y1, x, gpart);
  finish_kernel<1><<<NQ2 / 256, 256, 0, stream>>>(gpart, invlam, D12, u, r);

  // P = XP XP^T + eps I into M (MFMA), then blocked Cholesky (NSB=128)
  syrk_mfma_kernel<<<nsyrk, 256, 0, stream>>>(XP, NQ2, NQ2, M, FEPS);
  for (int k = 0; k < NSBLK; k++) {
    chol_diag128_kernel<<<1, 256, 0, stream>>>(M, Xinv, k);
    int rows_below = NQ2 - (k + 1) * NSB;
    if (rows_below > 0) {
      chol_panel128_kernel<<<rows_below / 128, 256, 0, stream>>>(M, Xinv, k);
      int m = NSBLK - 1 - k;
      chol_trail128_kernel<<<m * (m + 1) / 2, 256, 0, stream>>>(M, k);
    }
  }

  // solve P z = r
  fwd_solve_kernel<1><<<1, 512, 0, stream>>>(M, r, invlam, y);
  bwd_solve_kernel<<<1, 512, 0, stream>>>(M, y, z);

  // 2 steps of iterative refinement
  for (int it = 0; it < 2; it++) {
    tgemv_part_kernel<<<gdim, 256, 0, stream>>>(XP, z, gpart);
    finish_kernel<2><<<NQ2 / 256, 256, 0, stream>>>(gpart, invlam, D12, u, t);
    pz2_res_kernel<<<NQ2, 256, 0, stream>>>(XP, t, z, r, res);
    fwd_solve_kernel<1><<<1, 512, 0, stream>>>(M, res, invlam, y);
    bwd_solve_kernel<<<1, 512, 0, stream>>>(M, y, dz);
    axpy_kernel<<<NQ2 / 256, 256, 0, stream>>>(z, dz);
  }

  out_kernel<<<NQ2 / 256, 256, 0, stream>>>(z, B2, u, out);
}